// Round 16
// baseline (258.002 us; speedup 1.0000x reference)
//
#include <hip/hip_runtime.h>
#include <hip/hip_bf16.h>
#include <cstdint>

#define B_   16
#define C_   256
#define N_   8192
#define CN_  128
#define CL_  64
#define MID_ 128

typedef unsigned short u16;
typedef __attribute__((ext_vector_type(8))) short bf8;
typedef __attribute__((ext_vector_type(4))) float f4;

#define MFMA(a, bb, c) __builtin_amdgcn_mfma_f32_16x16x32_bf16(a, bb, c, 0, 0, 0)

// LDS-publish barrier without vmcnt drain (global prefetches stay in flight).
#define BAR() do {                                        \
    __builtin_amdgcn_sched_barrier(0);                    \
    asm volatile("s_waitcnt lgkmcnt(0)" ::: "memory");    \
    __builtin_amdgcn_s_barrier();                         \
    __builtin_amdgcn_sched_barrier(0);                    \
  } while (0)

__device__ inline u16 f2b(float v) {
  uint32_t b = __builtin_bit_cast(uint32_t, v);
  uint32_t r = (b + 0x7FFFu + ((b >> 16) & 1u)) >> 16;
  return (u16)r;
}
__device__ inline float b2f(u16 u) {
  uint32_t b = ((uint32_t)u) << 16;
  return __builtin_bit_cast(float, b);
}
__device__ inline void st4(u16* p, u16 a, u16 b, u16 c, u16 d) {
  unsigned long long v = (unsigned long long)a | ((unsigned long long)b << 16) |
                         ((unsigned long long)c << 32) | ((unsigned long long)d << 48);
  *(unsigned long long*)p = v;
}

// ---------------------------------------------------------------------------
// K0: wdnT[m][c] = sum_o wd[c][o]*wn[o][m] ; wdlT[m][c] = sum_o wd[c][128+o]*wl[o][m]
// ---------------------------------------------------------------------------
__global__ __launch_bounds__(256) void k_wfold(const float* __restrict__ wd,
                                               const float* __restrict__ wn,
                                               const float* __restrict__ wl,
                                               float* __restrict__ wdnT,
                                               float* __restrict__ wdlT) {
  const int idx = blockIdx.x * 256 + threadIdx.x;
  const int plane = idx >> 15;
  const int r = idx & 32767;
  const int c = r & 255, m = r >> 8;
  const float* wsrc = plane ? wl : wn;
  const float* wdrow = wd + c * 256 + plane * 128;
  float a0 = 0.f, a1 = 0.f, a2 = 0.f, a3 = 0.f;
  for (int o = 0; o < 128; o += 4) {
    a0 = fmaf(wdrow[o + 0], wsrc[(o + 0) * 128 + m], a0);
    a1 = fmaf(wdrow[o + 1], wsrc[(o + 1) * 128 + m], a1);
    a2 = fmaf(wdrow[o + 2], wsrc[(o + 2) * 128 + m], a2);
    a3 = fmaf(wdrow[o + 3], wsrc[(o + 3) * 128 + m], a3);
  }
  (plane ? wdlT : wdnT)[m * 256 + c] = (a0 + a1) + (a2 + a3);
}

// ---------------------------------------------------------------------------
// K1 (round-11 form): attp[cs][b][n*l] over 4 c-quarters; 1024 blocks, float2.
// ---------------------------------------------------------------------------
__global__ __launch_bounds__(256) void k_att(const float* __restrict__ curves,
                                             const float* __restrict__ w_att,
                                             float* __restrict__ attp) {
  const int blk = blockIdx.x;
  const int b = blk >> 6, seg = (blk >> 2) & 15, cs = blk & 3;
  const int e2 = seg * 512 + threadIdx.x * 2;
  const float* cb = curves + (size_t)b * C_ * CN_ * CL_ + (size_t)cs * 64 * 8192 + e2;
  const float* w = w_att + cs * 64;
  float2 a0 = {0.f, 0.f}, a1 = a0, a2 = a0, a3 = a0;
  #pragma unroll 4
  for (int c = 0; c < 64; c += 4) {
    const float w0 = w[c + 0], w1 = w[c + 1], w2 = w[c + 2], w3 = w[c + 3];
    float2 v0 = *(const float2*)&cb[(size_t)(c + 0) * 8192];
    float2 v1 = *(const float2*)&cb[(size_t)(c + 1) * 8192];
    float2 v2 = *(const float2*)&cb[(size_t)(c + 2) * 8192];
    float2 v3 = *(const float2*)&cb[(size_t)(c + 3) * 8192];
    a0.x = fmaf(w0, v0.x, a0.x); a0.y = fmaf(w0, v0.y, a0.y);
    a1.x = fmaf(w1, v1.x, a1.x); a1.y = fmaf(w1, v1.y, a1.y);
    a2.x = fmaf(w2, v2.x, a2.x); a2.y = fmaf(w2, v2.y, a2.y);
    a3.x = fmaf(w3, v3.x, a3.x); a3.y = fmaf(w3, v3.y, a3.y);
  }
  float2 a;
  a.x = (a0.x + a1.x) + (a2.x + a3.x);
  a.y = (a0.y + a1.y) + (a2.y + a3.y);
  *(float2*)&attp[(size_t)(cs * 16 + b) * 8192 + e2] = a;
}

// ---------------------------------------------------------------------------
// K2 (round-11 form): dual softmax, sums 4 partial planes on load
// ---------------------------------------------------------------------------
__global__ __launch_bounds__(256) void k_softmax(const float* __restrict__ attp,
                                                 float* __restrict__ smi,
                                                 float* __restrict__ sma) {
  __shared__ float T[CN_ * CL_];
  __shared__ float rmax[CN_], rrcp[CN_], cmax[CL_], crcp[CL_];
  const int b = blockIdx.x;
  const int tid = threadIdx.x;
  for (int idx = tid; idx < CN_ * CL_; idx += 256) {
    T[idx] = attp[(size_t)b * 8192 + idx]
           + attp[(size_t)(16 + b) * 8192 + idx]
           + attp[(size_t)(32 + b) * 8192 + idx]
           + attp[(size_t)(48 + b) * 8192 + idx];
  }
  __syncthreads();
  if (tid < 128) {
    const int n = tid;
    float mx = -1e30f;
    for (int l = 0; l < CL_; ++l) mx = fmaxf(mx, T[n * 64 + l]);
    float s = 0.f;
    for (int l = 0; l < CL_; ++l) s += __expf(T[n * 64 + l] - mx);
    rmax[n] = mx; rrcp[n] = 1.f / s;
  } else if (tid < 192) {
    const int l = tid - 128;
    float mx = -1e30f;
    for (int n = 0; n < CN_; ++n) mx = fmaxf(mx, T[n * 64 + l]);
    float s = 0.f;
    for (int n = 0; n < CN_; ++n) s += __expf(T[n * 64 + l] - mx);
    cmax[l] = mx; crcp[l] = 1.f / s;
  }
  __syncthreads();
  for (int idx = tid; idx < CN_ * CL_; idx += 256) {
    const int n = idx >> 6, l = idx & 63;
    const float v = T[idx];
    smi[b * 8192 + idx] = __expf(v - rmax[n]) * rrcp[n];
    sma[b * 8192 + idx] = __expf(v - cmax[l]) * crcp[l];
  }
}

// ---------------------------------------------------------------------------
// K3 (round-11 form): curve aggregation
// ---------------------------------------------------------------------------
__global__ __launch_bounds__(256) void k_agg(const float* __restrict__ curves,
                                             const float* __restrict__ smi,
                                             const float* __restrict__ sma,
                                             float* __restrict__ cinter,
                                             float* __restrict__ cintra) {
  __shared__ float P[CN_ * CL_];
  const int blk = blockIdx.x;
  const int b = blk >> 8, c = blk & 255;
  const int tid = threadIdx.x;
  const float* src = curves + (size_t)(b * 256 + c) * 8192;
  for (int i4 = tid; i4 < 2048; i4 += 256)
    *(float4*)&P[i4 * 4] = *(const float4*)&src[i4 * 4];
  __syncthreads();
  if (tid < 128) {
    const int n = tid;
    const float* sp = smi + (size_t)(b * 128 + n) * 64;
    float a[4] = {0.f, 0.f, 0.f, 0.f};
    for (int l0 = 0; l0 < 64; l0 += 4) {
      float4 pv = *(const float4*)&P[n * 64 + l0];
      float4 sv = *(const float4*)&sp[l0];
      a[0] = fmaf(pv.x, sv.x, a[0]);
      a[1] = fmaf(pv.y, sv.y, a[1]);
      a[2] = fmaf(pv.z, sv.z, a[2]);
      a[3] = fmaf(pv.w, sv.w, a[3]);
    }
    cinter[(size_t)(b * 256 + c) * 128 + n] = (a[0] + a[1]) + (a[2] + a[3]);
  } else if (tid < 192) {
    const int l = tid - 128;
    float a[4] = {0.f, 0.f, 0.f, 0.f};
    for (int n0 = 0; n0 < 128; n0 += 4) {
      a[0] = fmaf(P[(n0 + 0) * 64 + l], sma[(size_t)(b * 128 + n0 + 0) * 64 + l], a[0]);
      a[1] = fmaf(P[(n0 + 1) * 64 + l], sma[(size_t)(b * 128 + n0 + 1) * 64 + l], a[1]);
      a[2] = fmaf(P[(n0 + 2) * 64 + l], sma[(size_t)(b * 128 + n0 + 2) * 64 + l], a[2]);
      a[3] = fmaf(P[(n0 + 3) * 64 + l], sma[(size_t)(b * 128 + n0 + 3) * 64 + l], a[3]);
    }
    cintra[(size_t)(b * 256 + c) * 64 + l] = (a[0] + a[1]) + (a[2] + a[3]);
  }
}

// ---------------------------------------------------------------------------
// K4: a = wa@cinter ; bm = wb@cintra   (256 blocks)
// ---------------------------------------------------------------------------
__global__ __launch_bounds__(256) void k_ab(const float* __restrict__ wa,
                                            const float* __restrict__ wb,
                                            const float* __restrict__ cinter,
                                            const float* __restrict__ cintra,
                                            float* __restrict__ amat,
                                            float* __restrict__ bmat) {
  const int blk = blockIdx.x;
  const int b = blk >> 4, part = blk & 15;
  const int tid = threadIdx.x;
  for (int k = 0; k < 6; ++k) {
    const int g = part * 1536 + k * 256 + tid;
    if (g < 16384) {
      const int m = g >> 7, n = g & 127;
      const float* w = wa + m * 256;
      const float* ci = cinter + (size_t)b * 256 * 128 + n;
      float a[4] = {0.f, 0.f, 0.f, 0.f};
      for (int c0 = 0; c0 < 256; c0 += 4) {
        float4 w4 = *(const float4*)(w + c0);
        a[0] = fmaf(w4.x, ci[(c0 + 0) * 128], a[0]);
        a[1] = fmaf(w4.y, ci[(c0 + 1) * 128], a[1]);
        a[2] = fmaf(w4.z, ci[(c0 + 2) * 128], a[2]);
        a[3] = fmaf(w4.w, ci[(c0 + 3) * 128], a[3]);
      }
      amat[(size_t)b * 16384 + g] = (a[0] + a[1]) + (a[2] + a[3]);
    } else {
      const int i = g - 16384;
      const int m = i >> 6, l = i & 63;
      const float* w = wb + m * 256;
      const float* ct = cintra + (size_t)b * 256 * 64 + l;
      float a[4] = {0.f, 0.f, 0.f, 0.f};
      for (int c0 = 0; c0 < 256; c0 += 4) {
        float4 w4 = *(const float4*)(w + c0);
        a[0] = fmaf(w4.x, ct[(c0 + 0) * 64], a[0]);
        a[1] = fmaf(w4.y, ct[(c0 + 1) * 64], a[1]);
        a[2] = fmaf(w4.z, ct[(c0 + 2) * 64], a[2]);
        a[3] = fmaf(w4.w, ct[(c0 + 3) * 64], a[3]);
      }
      bmat[(size_t)b * 8192 + i] = (a[0] + a[1]) + (a[2] + a[3]);
    }
  }
}

// ---------------------------------------------------------------------------
// K6: fold per batch (unchanged).
// ---------------------------------------------------------------------------
__global__ __launch_bounds__(256) void k_fold(
    const float* __restrict__ wc,
    const float* __restrict__ amat, const float* __restrict__ bmat,
    const float* __restrict__ wdnT, const float* __restrict__ wdlT,
    u16* __restrict__ AnH, u16* __restrict__ AnL,
    u16* __restrict__ BlH, u16* __restrict__ BlL,
    u16* __restrict__ Wy) {
  __shared__ float S1[64 * 65], S2[64 * 65];
  const int blk = blockIdx.x;
  const int b = blk / 24, tile = blk - b * 24;
  const int tid = threadIdx.x;
  const int r = tid & 63, c4 = tid >> 6;
  float acc[16];
  #pragma unroll
  for (int i = 0; i < 16; ++i) acc[i] = 0.f;

  int n0 = 0, c0 = 0, type;
  if (tile < 8)       { type = 0; n0 = (tile >> 2) * 64; c0 = (tile & 3) * 64; }
  else if (tile < 12) { type = 1; c0 = (tile - 8) * 64; }
  else if (tile < 20) { type = 2; c0 = ((tile - 12) >> 1) * 64; n0 = ((tile - 12) & 1) * 64; }
  else                { type = 3; c0 = (tile - 20) * 64; }

  for (int kh = 0; kh < 2; ++kh) {
    __syncthreads();
    if (type == 0) {
      for (int it = 0; it < 16; ++it) {
        const int flat = it * 256 + tid, ml = flat >> 6, j = flat & 63;
        const int m = kh * 64 + ml;
        S1[ml * 65 + j] = wc[m * 256 + c0 + j];
        S2[ml * 65 + j] = amat[(size_t)b * 16384 + m * 128 + n0 + j];
      }
    } else if (type == 1) {
      for (int it = 0; it < 16; ++it) {
        const int flat = it * 256 + tid, ml = flat >> 6, j = flat & 63;
        const int m = kh * 64 + ml;
        S1[ml * 65 + j] = wc[m * 256 + c0 + j];
        S2[ml * 65 + j] = bmat[(size_t)b * 8192 + m * 64 + j];
      }
    } else if (type == 2) {
      for (int it = 0; it < 16; ++it) {
        const int flat = it * 256 + tid, ml = flat >> 6, j = flat & 63;
        const int m = kh * 64 + ml;
        S1[ml * 65 + j] = amat[(size_t)b * 16384 + m * 128 + n0 + j];
        S2[ml * 65 + j] = wdnT[m * 256 + c0 + j];
      }
    } else {
      for (int it = 0; it < 16; ++it) {
        const int flat = it * 256 + tid, ml = flat >> 6, j = flat & 63;
        const int m = kh * 64 + ml;
        S1[ml * 65 + j] = bmat[(size_t)b * 8192 + m * 64 + j];
        S2[ml * 65 + j] = wdlT[m * 256 + c0 + j];
      }
    }
    __syncthreads();
    for (int k = 0; k < 64; ++k) {
      const float va = S1[k * 65 + r];
      #pragma unroll
      for (int cc = 0; cc < 16; ++cc)
        acc[cc] = fmaf(va, S2[k * 65 + c4 * 16 + cc], acc[cc]);
    }
  }

  if (type == 0) {
    #pragma unroll
    for (int cc = 0; cc < 16; ++cc) {
      const float v = acc[cc];
      const u16 h = f2b(v);
      const size_t o = (size_t)b * 32768 + (n0 + c4 * 16 + cc) * 256 + c0 + r;
      AnH[o] = h; AnL[o] = f2b(v - b2f(h));
    }
  } else if (type == 1) {
    #pragma unroll
    for (int cc = 0; cc < 16; ++cc) {
      const float v = acc[cc];
      const u16 h = f2b(v);
      const size_t o = (size_t)b * 16384 + (c4 * 16 + cc) * 256 + c0 + r;
      BlH[o] = h; BlL[o] = f2b(v - b2f(h));
    }
  } else if (type == 2) {
    #pragma unroll
    for (int cc = 0; cc < 16; ++cc)
      Wy[(size_t)b * 49152 + (c0 + c4 * 16 + cc) * 192 + n0 + r] = f2b(acc[cc]);
  } else {
    #pragma unroll
    for (int cc = 0; cc < 16; ++cc)
      Wy[(size_t)b * 49152 + (c0 + c4 * 16 + cc) * 192 + 128 + r] = f2b(acc[cc]);
  }
}

// ---------------------------------------------------------------------------
// K7: r15 structure; SINGLE change: score K-steps 32 -> 64 (4 steps, barriers
// 16 -> 8). Per step: 96 MFMA/wave, A-tile [192][64] hi/lo, X [128][64].
// Swizzle: chunk ^ (row&7) over 8 chunks/row (row stride 128 B).
// u16 map: A hi@0 lo@12288 (end 24576) | X@24576 (end 32768)
//          E@0 (24576, overlays A) | Wy@24576 (8192, overlays X)
//          scL@32768 biL@33280. Total 33792 u16 = 67584 B.
// ---------------------------------------------------------------------------
__global__ __launch_bounds__(256, 2) void k_big(
    const float* __restrict__ x,
    const u16* __restrict__ AnH, const u16* __restrict__ AnL,
    const u16* __restrict__ BlH, const u16* __restrict__ BlL,
    const u16* __restrict__ Wy,
    const float* __restrict__ bng, const float* __restrict__ bnb,
    const float* __restrict__ bnm, const float* __restrict__ bnv,
    float* __restrict__ out) {
  __shared__ __align__(16) u16 LDS[33792];
  float* scL = (float*)(LDS + 32768);
  float* biL = (float*)(LDS + 33280);

  const int tid  = threadIdx.x;
  const int lane = tid & 63;
  const int wid  = tid >> 6;
  const int l15  = lane & 15;
  const int lg   = lane >> 4;
  const int p    = wid * 16 + l15;          // subtile-0 col (0..63); s1 = p+64
  const int blk  = blockIdx.x;
  const int wg   = ((blk & 7) << 7) | (blk >> 3);   // 1024 blocks = 8 XCD x 128
  const int b    = wg >> 6;
  const int p0g  = (wg & 63) << 7;
  const f4 zero4 = {0.f, 0.f, 0.f, 0.f};

  const u16* AnHb = AnH + ((size_t)b << 15);
  const u16* AnLb = AnL + ((size_t)b << 15);
  const u16* BlHb = BlH + ((size_t)b << 14);
  const u16* BlLb = BlL + ((size_t)b << 14);
  const u16* Wyb  = Wy  + (size_t)b * 49152;

  {
    const float scv = bng[tid] * rsqrtf(bnv[tid] + 1e-5f);
    scL[tid] = scv;
    biL[tid] = bnb[tid] - bnm[tid] * scv;
  }

  // ---- staging geometry
  // X: thread = (xp p-col, xh_ 32-c half); 32 scalar loads/step, 4 chunk writes.
  const int xp  = tid & 127;
  const int xh_ = tid >> 7;
  const float* xb = x + (size_t)b * C_ * N_ + p0g;
  int xo[4];
  #pragma unroll
  for (int jj = 0; jj < 4; ++jj) {
    const int ck = xh_ * 4 + jj;
    xo[jj] = 24576 + xp * 64 + ((ck ^ (xp & 7)) * 8);
  }
  // A: 12 chunks of 16B/thread; 3072 = 2 planes x 192 rows x 8 kc
  const u16* aSrc[12];
  int aLds[12];
  #pragma unroll
  for (int j = 0; j < 12; ++j) {
    const int cid = j * 256 + tid;
    const int plane = (cid >= 1536) ? 1 : 0;
    const int rr = cid - plane * 1536;
    const int row = rr >> 3, kc = rr & 7;
    const u16* base;
    if (row < 128) base = (plane ? AnLb : AnHb) + row * 256;
    else           base = (plane ? BlLb : BlHb) + (row - 128) * 256;
    aSrc[j] = base + 8 * (kc ^ (row & 7));
    aLds[j] = plane * 12288 + row * 64 + kc * 8;
  }
  // Wy: 4 chunks/thread (unchanged; region overlays dead X after score)
  const u16* wSrc[4];
  int wLds[4];
  #pragma unroll
  for (int j = 0; j < 4; ++j) {
    const int cid = j * 256 + tid;
    const int row = cid >> 2, kc = cid & 3;
    wSrc[j] = Wyb + row * 192 + 8 * (kc ^ ((row >> 1) & 3));
    wLds[j] = 24576 + row * 32 + kc * 8;
  }

  // ================= SCORE PHASE (4 steps of K=64) =================
  f4 accS[8][2], accA[4][2];
  #pragma unroll
  for (int t = 0; t < 8; ++t) { accS[t][0] = zero4; accS[t][1] = zero4; }
  #pragma unroll
  for (int t = 0; t < 4; ++t) { accA[t][0] = zero4; accA[t][1] = zero4; }

  bf8 aReg[12];
  float xRaw[32];

  // prologue: stage step 0
  #pragma unroll
  for (int j = 0; j < 12; ++j) aReg[j] = *(const bf8*)(aSrc[j]);
  #pragma unroll
  for (int jj = 0; jj < 32; ++jj)
    xRaw[jj] = xb[(size_t)(xh_ * 32 + jj) * N_ + xp];
  #pragma unroll
  for (int j = 0; j < 12; ++j) *(bf8*)(LDS + aLds[j]) = aReg[j];
  #pragma unroll
  for (int jj = 0; jj < 4; ++jj) {
    bf8 h;
    #pragma unroll
    for (int k2 = 0; k2 < 8; ++k2) h[k2] = (short)f2b(xRaw[jj * 8 + k2]);
    *(bf8*)(LDS + xo[jj]) = h;
  }
  BAR();

  #pragma unroll
  for (int q = 0; q < 4; ++q) {
    if (q < 3) {   // issue-early next step (X first: HBM; A: L2-hot)
      #pragma unroll
      for (int jj = 0; jj < 32; ++jj)
        xRaw[jj] = xb[(size_t)((q + 1) * 64 + xh_ * 32 + jj) * N_ + xp];
      #pragma unroll
      for (int j = 0; j < 12; ++j) aReg[j] = *(const bf8*)(aSrc[j] + (q + 1) * 64);
    }
    // compute step q: 2 k-sub-blocks of 32
    #pragma unroll
    for (int ks = 0; ks < 2; ++ks) {
      const int sx = 8 * (((ks << 2) | lg) ^ (l15 & 7));
      const bf8 xh0 = *(const bf8*)(LDS + 24576 + p * 64 + sx);
      const bf8 xh1 = *(const bf8*)(LDS + 24576 + (p + 64) * 64 + sx);
      #pragma unroll
      for (int t = 0; t < 8; ++t) {
        const int row = t * 16 + l15;
        const bf8 ah = *(const bf8*)(LDS + row * 64 + sx);
        const bf8 al = *(const bf8*)(LDS + 12288 + row * 64 + sx);
        accS[t][0] = MFMA(ah, xh0, accS[t][0]);
        accS[t][0] = MFMA(al, xh0, accS[t][0]);
        accS[t][1] = MFMA(ah, xh1, accS[t][1]);
        accS[t][1] = MFMA(al, xh1, accS[t][1]);
      }
      #pragma unroll
      for (int t = 0; t < 4; ++t) {
        const int row = 128 + t * 16 + l15;
        const bf8 ah = *(const bf8*)(LDS + row * 64 + sx);
        const bf8 al = *(const bf8*)(LDS + 12288 + row * 64 + sx);
        accA[t][0] = MFMA(ah, xh0, accA[t][0]);
        accA[t][0] = MFMA(al, xh0, accA[t][0]);
        accA[t][1] = MFMA(ah, xh1, accA[t][1]);
        accA[t][1] = MFMA(al, xh1, accA[t][1]);
      }
    }
    // convert X(q+1) while MFMAs drain
    bf8 nx[4];
    if (q < 3) {
      #pragma unroll
      for (int jj = 0; jj < 4; ++jj)
        #pragma unroll
        for (int k2 = 0; k2 < 8; ++k2)
          nx[jj][k2] = (short)f2b(xRaw[jj * 8 + k2]);
    }
    BAR();                    // all reads of tile q done
    if (q < 3) {
      #pragma unroll
      for (int j = 0; j < 12; ++j) *(bf8*)(LDS + aLds[j]) = aReg[j];
      #pragma unroll
      for (int jj = 0; jj < 4; ++jj) *(bf8*)(LDS + xo[jj]) = nx[jj];
      BAR();                  // tile q+1 visible
    }
  }

  // ================= SOFTMAX (wave-local, 2 subtiles) + E + Wy(0) =========
  bf8 wReg[4];
  #pragma unroll
  for (int j = 0; j < 4; ++j) wReg[j] = *(const bf8*)(wSrc[j]);   // Wy(0) early

  u16* E = LDS;   // [128 p][192 j], chunk-XOR by (p&7); overlays dead A region
  #pragma unroll
  for (int s = 0; s < 2; ++s) {
    const int ps = p + s * 64;
    float mx = -3.0e38f;
    #pragma unroll
    for (int t = 0; t < 8; ++t)
      #pragma unroll
      for (int r = 0; r < 4; ++r) mx = fmaxf(mx, accS[t][s][r]);
    mx = fmaxf(mx, __shfl_xor(mx, 16));
    mx = fmaxf(mx, __shfl_xor(mx, 32));
    float sum = 0.f;
    #pragma unroll
    for (int t = 0; t < 8; ++t)
      #pragma unroll
      for (int r = 0; r < 4; ++r) {
        const float e = __expf(accS[t][s][r] - mx);
        accS[t][s][r] = e; sum += e;
      }
    sum += __shfl_xor(sum, 16);
    sum += __shfl_xor(sum, 32);
    const float rcp = 1.f / sum;
    #pragma unroll
    for (int t = 0; t < 8; ++t) {
      const int j0 = t * 16 + lg * 4;
      const int chunk = j0 >> 3;
      const int csw = (chunk & ~7) | ((chunk & 7) ^ (ps & 7));
      st4(E + ps * 192 + csw * 8 + (j0 & 7),
          f2b(accS[t][s][0] * rcp), f2b(accS[t][s][1] * rcp),
          f2b(accS[t][s][2] * rcp), f2b(accS[t][s][3] * rcp));
    }
    float mx2 = -3.0e38f;
    #pragma unroll
    for (int t = 0; t < 4; ++t)
      #pragma unroll
      for (int r = 0; r < 4; ++r) mx2 = fmaxf(mx2, accA[t][s][r]);
    mx2 = fmaxf(mx2, __shfl_xor(mx2, 16));
    mx2 = fmaxf(mx2, __shfl_xor(mx2, 32));
    float sum2 = 0.f;
    #pragma unroll
    for (int t = 0; t < 4; ++t)
      #pragma unroll
      for (int r = 0; r < 4; ++r) {
        const float e = __expf(accA[t][s][r] - mx2);
        accA[t][s][r] = e; sum2 += e;
      }
    sum2 += __shfl_xor(sum2, 16);
    sum2 += __shfl_xor(sum2, 32);
    const float rcp2 = 1.f / sum2;
    #pragma unroll
    for (int t = 0; t < 4; ++t) {
      const int j0 = 128 + t * 16 + lg * 4;
      const int chunk = j0 >> 3;
      const int csw = (chunk & ~7) | ((chunk & 7) ^ (ps & 7));
      st4(E + ps * 192 + csw * 8 + (j0 & 7),
          f2b(accA[t][s][0] * rcp2), f2b(accA[t][s][1] * rcp2),
          f2b(accA[t][s][2] * rcp2), f2b(accA[t][s][3] * rcp2));
    }
  }
  // Wy(0) into 24576.. (X region, dead after final score BAR)
  #pragma unroll
  for (int j = 0; j < 4; ++j) *(bf8*)(LDS + wLds[j]) = wReg[j];
  BAR();                      // E + Wy(0) visible

  // ================= OUT PHASE: y = Wy @ E (K=192, 6 steps) ===============
  f4 acc8[16][2];
  #pragma unroll
  for (int t = 0; t < 16; ++t) { acc8[t][0] = zero4; acc8[t][1] = zero4; }

  #pragma unroll
  for (int q = 0; q < 6; ++q) {
    if (q < 5) {
      #pragma unroll
      for (int j = 0; j < 4; ++j) wReg[j] = *(const bf8*)(wSrc[j] + (q + 1) * 32);
    }
    const int jchunk = q * 4 + lg;
    const int cs0 = (jchunk & ~7) | ((jchunk & 7) ^ (p & 7));
    const bf8 ef0 = *(const bf8*)(E + p * 192 + cs0 * 8);
    const bf8 ef1 = *(const bf8*)(E + (p + 64) * 192 + cs0 * 8);
    #pragma unroll
    for (int t = 0; t < 16; ++t) {
      const int row = t * 16 + l15;
      const int sw = 8 * (lg ^ ((row >> 1) & 3));
      const bf8 wf = *(const bf8*)(LDS + 24576 + row * 32 + sw);
      acc8[t][0] = MFMA(wf, ef0, acc8[t][0]);
      acc8[t][1] = MFMA(wf, ef1, acc8[t][1]);
    }
    BAR();                    // all reads of Wy(q) done
    if (q < 5) {
      #pragma unroll
      for (int j = 0; j < 4; ++j) *(bf8*)(LDS + wLds[j]) = wReg[j];
      BAR();                  // Wy(q+1) visible
    }
  }

  // ================= EPILOGUE: BN + residual + leaky ======================
  const size_t pcol = (size_t)p0g + p;
  #pragma unroll
  for (int t = 0; t < 16; ++t) {
    #pragma unroll
    for (int r = 0; r < 4; ++r) {
      const int c = t * 16 + lg * 4 + r;
      const float sc = scL[c], bi = biL[c];
      const size_t o0 = (((size_t)b * 256 + c) << 13) + pcol;
      const float z0 = x[o0] + acc8[t][0][r] * sc + bi;
      out[o0] = z0 > 0.f ? z0 : 0.2f * z0;
      const size_t o1 = o0 + 64;
      const float z1 = x[o1] + acc8[t][1][r] * sc + bi;
      out[o1] = z1 > 0.f ? z1 : 0.2f * z1;
    }
  }
}

// ---------------------------------------------------------------------------
extern "C" void kernel_launch(void* const* d_in, const int* in_sizes, int n_in,
                              void* d_out, int out_size, void* d_ws, size_t ws_size,
                              hipStream_t stream) {
  const float* x      = (const float*)d_in[0];
  const float* curves = (const float*)d_in[1];
  const float* w_att  = (const float*)d_in[2];
  const float* wa     = (const float*)d_in[3];
  const float* wb     = (const float*)d_in[4];
  const float* wc     = (const float*)d_in[5];
  const float* wn     = (const float*)d_in[6];
  const float* wl     = (const float*)d_in[7];
  const float* wd     = (const float*)d_in[8];
  const float* bng    = (const float*)d_in[9];
  const float* bnb    = (const float*)d_in[10];
  const float* bnm    = (const float*)d_in[11];
  const float* bnv    = (const float*)d_in[12];
  float* out = (float*)d_out;
  float* ws  = (float*)d_ws;

  float* smi    = ws + 131072;
  float* sma    = ws + 262144;
  float* cinter = ws + 393216;
  float* cintra = ws + 917504;
  float* amat   = ws + 1179648;
  float* bmat   = ws + 1441792;
  float* attp   = ws + 1179648;
  float* wdnT   = ws + 1703936;
  float* wdlT   = ws + 1736704;

  u16* wsb = (u16*)d_ws;
  u16* AnH = wsb;
  u16* AnL = wsb + 524288;
  u16* BlH = wsb + 1048576;
  u16* BlL = wsb + 1310720;
  u16* Wyp = wsb + 1572864;

  k_wfold  <<<dim3(256),      dim3(256), 0, stream>>>(wd, wn, wl, wdnT, wdlT);
  k_att    <<<dim3(B_ * 64),  dim3(256), 0, stream>>>(curves, w_att, attp);
  k_softmax<<<dim3(B_),       dim3(256), 0, stream>>>(attp, smi, sma);
  k_agg    <<<dim3(B_ * C_),  dim3(256), 0, stream>>>(curves, smi, sma, cinter, cintra);
  k_ab     <<<dim3(B_ * 16),  dim3(256), 0, stream>>>(wa, wb, cinter, cintra, amat, bmat);
  k_fold   <<<dim3(B_ * 24),  dim3(256), 0, stream>>>(wc, amat, bmat, wdnT, wdlT,
                                                      AnH, AnL, BlH, BlL, Wyp);
  k_big    <<<dim3(1024),     dim3(256), 0, stream>>>(x, AnH, AnL, BlH, BlL, Wyp,
                                                      bng, bnb, bnm, bnv, out);
}

// Round 17
// 240.092 us; speedup vs baseline: 1.0746x; 1.0746x over previous
//
#include <hip/hip_runtime.h>
#include <hip/hip_bf16.h>
#include <cstdint>

#define B_   16
#define C_   256
#define N_   8192
#define CN_  128
#define CL_  64
#define MID_ 128

typedef unsigned short u16;
typedef __attribute__((ext_vector_type(8))) short bf8;
typedef __attribute__((ext_vector_type(4))) float f4;

#define MFMA(a, bb, c) __builtin_amdgcn_mfma_f32_16x16x32_bf16(a, bb, c, 0, 0, 0)

// LDS-publish barrier without vmcnt drain (global prefetches stay in flight).
#define BAR() do {                                        \
    __builtin_amdgcn_sched_barrier(0);                    \
    asm volatile("s_waitcnt lgkmcnt(0)" ::: "memory");    \
    __builtin_amdgcn_s_barrier();                         \
    __builtin_amdgcn_sched_barrier(0);                    \
  } while (0)

__device__ inline u16 f2b(float v) {
  uint32_t b = __builtin_bit_cast(uint32_t, v);
  uint32_t r = (b + 0x7FFFu + ((b >> 16) & 1u)) >> 16;
  return (u16)r;
}
__device__ inline float b2f(u16 u) {
  uint32_t b = ((uint32_t)u) << 16;
  return __builtin_bit_cast(float, b);
}
__device__ inline void st4(u16* p, u16 a, u16 b, u16 c, u16 d) {
  unsigned long long v = (unsigned long long)a | ((unsigned long long)b << 16) |
                         ((unsigned long long)c << 32) | ((unsigned long long)d << 48);
  *(unsigned long long*)p = v;
}

// ---------------------------------------------------------------------------
// K0a: wdnT[m][c] = sum_o wd[c][o]*wn[o][m] ; wdlT[m][c] = sum_o wd[c][128+o]*wl[o][m]
// ---------------------------------------------------------------------------
__global__ __launch_bounds__(256) void k_wfold(const float* __restrict__ wd,
                                               const float* __restrict__ wn,
                                               const float* __restrict__ wl,
                                               float* __restrict__ wdnT,
                                               float* __restrict__ wdlT) {
  const int idx = blockIdx.x * 256 + threadIdx.x;
  const int plane = idx >> 15;
  const int r = idx & 32767;
  const int c = r & 255, m = r >> 8;
  const float* wsrc = plane ? wl : wn;
  const float* wdrow = wd + c * 256 + plane * 128;
  float a0 = 0.f, a1 = 0.f, a2 = 0.f, a3 = 0.f;
  for (int o = 0; o < 128; o += 4) {
    a0 = fmaf(wdrow[o + 0], wsrc[(o + 0) * 128 + m], a0);
    a1 = fmaf(wdrow[o + 1], wsrc[(o + 1) * 128 + m], a1);
    a2 = fmaf(wdrow[o + 2], wsrc[(o + 2) * 128 + m], a2);
    a3 = fmaf(wdrow[o + 3], wsrc[(o + 3) * 128 + m], a3);
  }
  (plane ? wdlT : wdnT)[m * 256 + c] = (a0 + a1) + (a2 + a3);
}

// ---------------------------------------------------------------------------
// K0b: batch-independent folds (all [256 c][256 cc], K=128 over m):
//   Wac = wa^T@wc   Wna = wa^T@wdnT   Wbc = wb^T@wc   Wlb = wb^T@wdlT
// ---------------------------------------------------------------------------
__global__ __launch_bounds__(256) void k_wfold2(
    const float* __restrict__ wa, const float* __restrict__ wb,
    const float* __restrict__ wc,
    const float* __restrict__ wdnT, const float* __restrict__ wdlT,
    float* __restrict__ Wac, float* __restrict__ Wna,
    float* __restrict__ Wbc, float* __restrict__ Wlb) {
  const int idx = blockIdx.x * 256 + threadIdx.x;   // 262144
  const int quad = idx >> 16;
  const int r = idx & 65535;
  const int cc = r & 255, c = r >> 8;
  const float* L = (quad & 2) ? wb : wa;
  const float* R = (quad & 1) ? ((quad & 2) ? wdlT : wdnT) : wc;
  float a0 = 0.f, a1 = 0.f, a2 = 0.f, a3 = 0.f;
  for (int m = 0; m < 128; m += 4) {
    a0 = fmaf(L[(m + 0) * 256 + c], R[(m + 0) * 256 + cc], a0);
    a1 = fmaf(L[(m + 1) * 256 + c], R[(m + 1) * 256 + cc], a1);
    a2 = fmaf(L[(m + 2) * 256 + c], R[(m + 2) * 256 + cc], a2);
    a3 = fmaf(L[(m + 3) * 256 + c], R[(m + 3) * 256 + cc], a3);
  }
  float* O = (quad == 0) ? Wac : (quad == 1) ? Wna : (quad == 2) ? Wbc : Wlb;
  O[c * 256 + cc] = (a0 + a1) + (a2 + a3);
}

// ---------------------------------------------------------------------------
// K1 (round-11 form): attp[cs][b][n*l] over 4 c-quarters; 1024 blocks, float2.
// ---------------------------------------------------------------------------
__global__ __launch_bounds__(256) void k_att(const float* __restrict__ curves,
                                             const float* __restrict__ w_att,
                                             float* __restrict__ attp) {
  const int blk = blockIdx.x;
  const int b = blk >> 6, seg = (blk >> 2) & 15, cs = blk & 3;
  const int e2 = seg * 512 + threadIdx.x * 2;
  const float* cb = curves + (size_t)b * C_ * CN_ * CL_ + (size_t)cs * 64 * 8192 + e2;
  const float* w = w_att + cs * 64;
  float2 a0 = {0.f, 0.f}, a1 = a0, a2 = a0, a3 = a0;
  #pragma unroll 4
  for (int c = 0; c < 64; c += 4) {
    const float w0 = w[c + 0], w1 = w[c + 1], w2 = w[c + 2], w3 = w[c + 3];
    float2 v0 = *(const float2*)&cb[(size_t)(c + 0) * 8192];
    float2 v1 = *(const float2*)&cb[(size_t)(c + 1) * 8192];
    float2 v2 = *(const float2*)&cb[(size_t)(c + 2) * 8192];
    float2 v3 = *(const float2*)&cb[(size_t)(c + 3) * 8192];
    a0.x = fmaf(w0, v0.x, a0.x); a0.y = fmaf(w0, v0.y, a0.y);
    a1.x = fmaf(w1, v1.x, a1.x); a1.y = fmaf(w1, v1.y, a1.y);
    a2.x = fmaf(w2, v2.x, a2.x); a2.y = fmaf(w2, v2.y, a2.y);
    a3.x = fmaf(w3, v3.x, a3.x); a3.y = fmaf(w3, v3.y, a3.y);
  }
  float2 a;
  a.x = (a0.x + a1.x) + (a2.x + a3.x);
  a.y = (a0.y + a1.y) + (a2.y + a3.y);
  *(float2*)&attp[(size_t)(cs * 16 + b) * 8192 + e2] = a;
}

// ---------------------------------------------------------------------------
// K2 (round-11 form): dual softmax, sums 4 partial planes on load
// ---------------------------------------------------------------------------
__global__ __launch_bounds__(256) void k_softmax(const float* __restrict__ attp,
                                                 float* __restrict__ smi,
                                                 float* __restrict__ sma) {
  __shared__ float T[CN_ * CL_];
  __shared__ float rmax[CN_], rrcp[CN_], cmax[CL_], crcp[CL_];
  const int b = blockIdx.x;
  const int tid = threadIdx.x;
  for (int idx = tid; idx < CN_ * CL_; idx += 256) {
    T[idx] = attp[(size_t)b * 8192 + idx]
           + attp[(size_t)(16 + b) * 8192 + idx]
           + attp[(size_t)(32 + b) * 8192 + idx]
           + attp[(size_t)(48 + b) * 8192 + idx];
  }
  __syncthreads();
  if (tid < 128) {
    const int n = tid;
    float mx = -1e30f;
    for (int l = 0; l < CL_; ++l) mx = fmaxf(mx, T[n * 64 + l]);
    float s = 0.f;
    for (int l = 0; l < CL_; ++l) s += __expf(T[n * 64 + l] - mx);
    rmax[n] = mx; rrcp[n] = 1.f / s;
  } else if (tid < 192) {
    const int l = tid - 128;
    float mx = -1e30f;
    for (int n = 0; n < CN_; ++n) mx = fmaxf(mx, T[n * 64 + l]);
    float s = 0.f;
    for (int n = 0; n < CN_; ++n) s += __expf(T[n * 64 + l] - mx);
    cmax[l] = mx; crcp[l] = 1.f / s;
  }
  __syncthreads();
  for (int idx = tid; idx < CN_ * CL_; idx += 256) {
    const int n = idx >> 6, l = idx & 63;
    const float v = T[idx];
    smi[b * 8192 + idx] = __expf(v - rmax[n]) * rrcp[n];
    sma[b * 8192 + idx] = __expf(v - cmax[l]) * crcp[l];
  }
}

// ---------------------------------------------------------------------------
// K3 (round-11 form): curve aggregation
// ---------------------------------------------------------------------------
__global__ __launch_bounds__(256) void k_agg(const float* __restrict__ curves,
                                             const float* __restrict__ smi,
                                             const float* __restrict__ sma,
                                             float* __restrict__ cinter,
                                             float* __restrict__ cintra) {
  __shared__ float P[CN_ * CL_];
  const int blk = blockIdx.x;
  const int b = blk >> 8, c = blk & 255;
  const int tid = threadIdx.x;
  const float* src = curves + (size_t)(b * 256 + c) * 8192;
  for (int i4 = tid; i4 < 2048; i4 += 256)
    *(float4*)&P[i4 * 4] = *(const float4*)&src[i4 * 4];
  __syncthreads();
  if (tid < 128) {
    const int n = tid;
    const float* sp = smi + (size_t)(b * 128 + n) * 64;
    float a[4] = {0.f, 0.f, 0.f, 0.f};
    for (int l0 = 0; l0 < 64; l0 += 4) {
      float4 pv = *(const float4*)&P[n * 64 + l0];
      float4 sv = *(const float4*)&sp[l0];
      a[0] = fmaf(pv.x, sv.x, a[0]);
      a[1] = fmaf(pv.y, sv.y, a[1]);
      a[2] = fmaf(pv.z, sv.z, a[2]);
      a[3] = fmaf(pv.w, sv.w, a[3]);
    }
    cinter[(size_t)(b * 256 + c) * 128 + n] = (a[0] + a[1]) + (a[2] + a[3]);
  } else if (tid < 192) {
    const int l = tid - 128;
    float a[4] = {0.f, 0.f, 0.f, 0.f};
    for (int n0 = 0; n0 < 128; n0 += 4) {
      a[0] = fmaf(P[(n0 + 0) * 64 + l], sma[(size_t)(b * 128 + n0 + 0) * 64 + l], a[0]);
      a[1] = fmaf(P[(n0 + 1) * 64 + l], sma[(size_t)(b * 128 + n0 + 1) * 64 + l], a[1]);
      a[2] = fmaf(P[(n0 + 2) * 64 + l], sma[(size_t)(b * 128 + n0 + 2) * 64 + l], a[2]);
      a[3] = fmaf(P[(n0 + 3) * 64 + l], sma[(size_t)(b * 128 + n0 + 3) * 64 + l], a[3]);
    }
    cintra[(size_t)(b * 256 + c) * 64 + l] = (a[0] + a[1]) + (a[2] + a[3]);
  }
}

// ---------------------------------------------------------------------------
// K6: fold per batch, K=256 over c directly from cinter/cintra (k_ab folded
// away via Wac/Wna/Wbc/Wlb). Same tile map & outputs as before.
// ---------------------------------------------------------------------------
__global__ __launch_bounds__(256) void k_fold(
    const float* __restrict__ cinter, const float* __restrict__ cintra,
    const float* __restrict__ Wac, const float* __restrict__ Wna,
    const float* __restrict__ Wbc, const float* __restrict__ Wlb,
    u16* __restrict__ AnH, u16* __restrict__ AnL,
    u16* __restrict__ BlH, u16* __restrict__ BlL,
    u16* __restrict__ Wy) {
  __shared__ float S1[64 * 65], S2[64 * 65];
  const int blk = blockIdx.x;
  const int b = blk / 24, tile = blk - b * 24;
  const int tid = threadIdx.x;
  const int r = tid & 63, c4 = tid >> 6;
  float acc[16];
  #pragma unroll
  for (int i = 0; i < 16; ++i) acc[i] = 0.f;

  int n0 = 0, c0 = 0, type;
  if (tile < 8)       { type = 0; n0 = (tile >> 2) * 64; c0 = (tile & 3) * 64; }
  else if (tile < 12) { type = 1; c0 = (tile - 8) * 64; }
  else if (tile < 20) { type = 2; c0 = ((tile - 12) >> 1) * 64; n0 = ((tile - 12) & 1) * 64; }
  else                { type = 3; c0 = (tile - 20) * 64; }

  const float* cib = cinter + (size_t)b * 32768;   // [256 c][128 n]
  const float* ctb = cintra + (size_t)b * 16384;   // [256 c][64 l]

  for (int kh = 0; kh < 4; ++kh) {
    __syncthreads();
    if (type == 0) {            // S1=Wac[c][c0+j], S2=cinter[c][n0+j]
      for (int it = 0; it < 16; ++it) {
        const int flat = it * 256 + tid, cl = flat >> 6, j = flat & 63;
        const int c = kh * 64 + cl;
        S1[cl * 65 + j] = Wac[c * 256 + c0 + j];
        S2[cl * 65 + j] = cib[c * 128 + n0 + j];
      }
    } else if (type == 1) {     // S1=Wbc, S2=cintra[c][j]
      for (int it = 0; it < 16; ++it) {
        const int flat = it * 256 + tid, cl = flat >> 6, j = flat & 63;
        const int c = kh * 64 + cl;
        S1[cl * 65 + j] = Wbc[c * 256 + c0 + j];
        S2[cl * 65 + j] = ctb[c * 64 + j];
      }
    } else if (type == 2) {     // S1=cinter[c][n0+j], S2=Wna[c][c0+j]
      for (int it = 0; it < 16; ++it) {
        const int flat = it * 256 + tid, cl = flat >> 6, j = flat & 63;
        const int c = kh * 64 + cl;
        S1[cl * 65 + j] = cib[c * 128 + n0 + j];
        S2[cl * 65 + j] = Wna[c * 256 + c0 + j];
      }
    } else {                    // S1=cintra[c][j], S2=Wlb[c][c0+j]
      for (int it = 0; it < 16; ++it) {
        const int flat = it * 256 + tid, cl = flat >> 6, j = flat & 63;
        const int c = kh * 64 + cl;
        S1[cl * 65 + j] = ctb[c * 64 + j];
        S2[cl * 65 + j] = Wlb[c * 256 + c0 + j];
      }
    }
    __syncthreads();
    for (int k = 0; k < 64; ++k) {
      const float va = S1[k * 65 + r];
      #pragma unroll
      for (int cc = 0; cc < 16; ++cc)
        acc[cc] = fmaf(va, S2[k * 65 + c4 * 16 + cc], acc[cc]);
    }
  }

  if (type == 0) {        // O[c'][n'] -> An[n0+n'][c0+c'] hi/lo
    #pragma unroll
    for (int cc = 0; cc < 16; ++cc) {
      const float v = acc[cc];
      const u16 h = f2b(v);
      const size_t o = (size_t)b * 32768 + (n0 + c4 * 16 + cc) * 256 + c0 + r;
      AnH[o] = h; AnL[o] = f2b(v - b2f(h));
    }
  } else if (type == 1) { // O[c'][l'] -> Bl[l'][c0+c'] hi/lo
    #pragma unroll
    for (int cc = 0; cc < 16; ++cc) {
      const float v = acc[cc];
      const u16 h = f2b(v);
      const size_t o = (size_t)b * 16384 + (c4 * 16 + cc) * 256 + c0 + r;
      BlH[o] = h; BlL[o] = f2b(v - b2f(h));
    }
  } else if (type == 2) { // O[n'][c'] -> Wy[c0+c'][n0+n']
    #pragma unroll
    for (int cc = 0; cc < 16; ++cc)
      Wy[(size_t)b * 49152 + (c0 + c4 * 16 + cc) * 192 + n0 + r] = f2b(acc[cc]);
  } else {                // O[l'][c'] -> Wy[c0+c'][128+l']
    #pragma unroll
    for (int cc = 0; cc < 16; ++cc)
      Wy[(size_t)b * 49152 + (c0 + c4 * 16 + cc) * 192 + 128 + r] = f2b(acc[cc]);
  }
}

// ---------------------------------------------------------------------------
// K7: round-15 k_big verbatim (best-measured 100.5µs form): p-tile 128,
// 4 waves x 2 p-subtiles, X plain-bf16 (2-term score), 8 x K=32 steps,
// single-buffered 2-BAR steps, launch_bounds(256,2), LDS 66 KB.
// ---------------------------------------------------------------------------
__global__ __launch_bounds__(256, 2) void k_big(
    const float* __restrict__ x,
    const u16* __restrict__ AnH, const u16* __restrict__ AnL,
    const u16* __restrict__ BlH, const u16* __restrict__ BlL,
    const u16* __restrict__ Wy,
    const float* __restrict__ bng, const float* __restrict__ bnb,
    const float* __restrict__ bnm, const float* __restrict__ bnv,
    float* __restrict__ out) {
  __shared__ __align__(16) u16 LDS[33792];
  float* scL = (float*)(LDS + 32768);
  float* biL = (float*)(LDS + 33280);

  const int tid  = threadIdx.x;
  const int lane = tid & 63;
  const int wid  = tid >> 6;
  const int l15  = lane & 15;
  const int lg   = lane >> 4;
  const int p    = wid * 16 + l15;
  const int blk  = blockIdx.x;
  const int wg   = ((blk & 7) << 7) | (blk >> 3);
  const int b    = wg >> 6;
  const int p0g  = (wg & 63) << 7;
  const f4 zero4 = {0.f, 0.f, 0.f, 0.f};

  const u16* AnHb = AnH + ((size_t)b << 15);
  const u16* AnLb = AnL + ((size_t)b << 15);
  const u16* BlHb = BlH + ((size_t)b << 14);
  const u16* BlLb = BlL + ((size_t)b << 14);
  const u16* Wyb  = Wy  + (size_t)b * 49152;

  {
    const float scv = bng[tid] * rsqrtf(bnv[tid] + 1e-5f);
    scL[tid] = scv;
    biL[tid] = bnb[tid] - bnm[tid] * scv;
  }

  const int xp  = tid & 127;
  const int xkc = tid >> 7;
  const float* xb = x + (size_t)b * C_ * N_ + p0g;
  const int xswp = (xp >> 1) & 3;
  const int xo0 = xp * 32 + (((2 * xkc + 0) ^ xswp) * 8);
  const int xo1 = xp * 32 + (((2 * xkc + 1) ^ xswp) * 8);
  const u16* aSrc[6];
  int aLds[6];
  #pragma unroll
  for (int j = 0; j < 6; ++j) {
    const int cid = j * 256 + tid;
    const int plane = (cid >= 768) ? 1 : 0;
    const int rr = cid - plane * 768;
    const int row = rr >> 2, kc = rr & 3;
    const u16* base;
    if (row < 128) base = (plane ? AnLb : AnHb) + row * 256;
    else           base = (plane ? BlLb : BlHb) + (row - 128) * 256;
    aSrc[j] = base + 8 * (kc ^ ((row >> 1) & 3));
    aLds[j] = plane * 6144 + row * 32 + kc * 8;
  }
  const u16* wSrc[4];
  int wLds[4];
  #pragma unroll
  for (int j = 0; j < 4; ++j) {
    const int cid = j * 256 + tid;
    const int row = cid >> 2, kc = cid & 3;
    wSrc[j] = Wyb + row * 192 + 8 * (kc ^ ((row >> 1) & 3));
    wLds[j] = 24576 + row * 32 + kc * 8;
  }

  // ================= SCORE PHASE =================
  f4 accS[8][2], accA[4][2];
  #pragma unroll
  for (int t = 0; t < 8; ++t) { accS[t][0] = zero4; accS[t][1] = zero4; }
  #pragma unroll
  for (int t = 0; t < 4; ++t) { accA[t][0] = zero4; accA[t][1] = zero4; }

  bf8 aReg[6];
  float xRaw[2][16];

  #pragma unroll
  for (int j = 0; j < 6; ++j) aReg[j] = *(const bf8*)(aSrc[j]);
  #pragma unroll
  for (int jj = 0; jj < 16; ++jj)
    xRaw[0][jj] = xb[(size_t)(xkc * 16 + jj) * N_ + xp];
  #pragma unroll
  for (int j = 0; j < 6; ++j) *(bf8*)(LDS + aLds[j]) = aReg[j];
  {
    bf8 h0, h1;
    #pragma unroll
    for (int jj = 0; jj < 8; ++jj) {
      h0[jj] = (short)f2b(xRaw[0][jj]);
      h1[jj] = (short)f2b(xRaw[0][8 + jj]);
    }
    *(bf8*)(LDS + 12288 + xo0) = h0;
    *(bf8*)(LDS + 12288 + xo1) = h1;
  }
  #pragma unroll
  for (int jj = 0; jj < 16; ++jj)
    xRaw[1][jj] = xb[(size_t)(32 + xkc * 16 + jj) * N_ + xp];
  BAR();

  const int rswp = (p >> 1) & 3;
  #pragma unroll
  for (int q = 0; q < 8; ++q) {
    if (q < 7) {
      #pragma unroll
      for (int j = 0; j < 6; ++j) aReg[j] = *(const bf8*)(aSrc[j] + (q + 1) * 32);
    }
    if (q < 6) {
      #pragma unroll
      for (int jj = 0; jj < 16; ++jj)
        xRaw[q & 1][jj] = xb[(size_t)((q + 2) * 32 + xkc * 16 + jj) * N_ + xp];
    }
    const bf8 xh0 = *(const bf8*)(LDS + 12288 + p * 32 + ((lg ^ rswp) * 8));
    const bf8 xh1 = *(const bf8*)(LDS + 12288 + (p + 64) * 32 + ((lg ^ rswp) * 8));
    #pragma unroll
    for (int t = 0; t < 8; ++t) {
      const int row = t * 16 + l15;
      const int sw = 8 * (lg ^ ((row >> 1) & 3));
      const bf8 ah = *(const bf8*)(LDS + row * 32 + sw);
      const bf8 al = *(const bf8*)(LDS + 6144 + row * 32 + sw);
      accS[t][0] = MFMA(ah, xh0, accS[t][0]);
      accS[t][0] = MFMA(al, xh0, accS[t][0]);
      accS[t][1] = MFMA(ah, xh1, accS[t][1]);
      accS[t][1] = MFMA(al, xh1, accS[t][1]);
    }
    #pragma unroll
    for (int t = 0; t < 4; ++t) {
      const int row = 128 + t * 16 + l15;
      const int sw = 8 * (lg ^ ((row >> 1) & 3));
      const bf8 ah = *(const bf8*)(LDS + row * 32 + sw);
      const bf8 al = *(const bf8*)(LDS + 6144 + row * 32 + sw);
      accA[t][0] = MFMA(ah, xh0, accA[t][0]);
      accA[t][0] = MFMA(al, xh0, accA[t][0]);
      accA[t][1] = MFMA(ah, xh1, accA[t][1]);
      accA[t][1] = MFMA(al, xh1, accA[t][1]);
    }
    bf8 nh0, nh1;
    if (q < 7) {
      #pragma unroll
      for (int jj = 0; jj < 8; ++jj) {
        nh0[jj] = (short)f2b(xRaw[(q + 1) & 1][jj]);
        nh1[jj] = (short)f2b(xRaw[(q + 1) & 1][8 + jj]);
      }
    }
    BAR();
    if (q < 7) {
      #pragma unroll
      for (int j = 0; j < 6; ++j) *(bf8*)(LDS + aLds[j]) = aReg[j];
      *(bf8*)(LDS + 12288 + xo0) = nh0;
      *(bf8*)(LDS + 12288 + xo1) = nh1;
      BAR();
    }
  }

  // ================= SOFTMAX + E + Wy(0) =================
  bf8 wReg[4];
  #pragma unroll
  for (int j = 0; j < 4; ++j) wReg[j] = *(const bf8*)(wSrc[j]);

  u16* E = LDS;
  #pragma unroll
  for (int s = 0; s < 2; ++s) {
    const int ps = p + s * 64;
    float mx = -3.0e38f;
    #pragma unroll
    for (int t = 0; t < 8; ++t)
      #pragma unroll
      for (int r = 0; r < 4; ++r) mx = fmaxf(mx, accS[t][s][r]);
    mx = fmaxf(mx, __shfl_xor(mx, 16));
    mx = fmaxf(mx, __shfl_xor(mx, 32));
    float sum = 0.f;
    #pragma unroll
    for (int t = 0; t < 8; ++t)
      #pragma unroll
      for (int r = 0; r < 4; ++r) {
        const float e = __expf(accS[t][s][r] - mx);
        accS[t][s][r] = e; sum += e;
      }
    sum += __shfl_xor(sum, 16);
    sum += __shfl_xor(sum, 32);
    const float rcp = 1.f / sum;
    #pragma unroll
    for (int t = 0; t < 8; ++t) {
      const int j0 = t * 16 + lg * 4;
      const int chunk = j0 >> 3;
      const int csw = (chunk & ~7) | ((chunk & 7) ^ (ps & 7));
      st4(E + ps * 192 + csw * 8 + (j0 & 7),
          f2b(accS[t][s][0] * rcp), f2b(accS[t][s][1] * rcp),
          f2b(accS[t][s][2] * rcp), f2b(accS[t][s][3] * rcp));
    }
    float mx2 = -3.0e38f;
    #pragma unroll
    for (int t = 0; t < 4; ++t)
      #pragma unroll
      for (int r = 0; r < 4; ++r) mx2 = fmaxf(mx2, accA[t][s][r]);
    mx2 = fmaxf(mx2, __shfl_xor(mx2, 16));
    mx2 = fmaxf(mx2, __shfl_xor(mx2, 32));
    float sum2 = 0.f;
    #pragma unroll
    for (int t = 0; t < 4; ++t)
      #pragma unroll
      for (int r = 0; r < 4; ++r) {
        const float e = __expf(accA[t][s][r] - mx2);
        accA[t][s][r] = e; sum2 += e;
      }
    sum2 += __shfl_xor(sum2, 16);
    sum2 += __shfl_xor(sum2, 32);
    const float rcp2 = 1.f / sum2;
    #pragma unroll
    for (int t = 0; t < 4; ++t) {
      const int j0 = 128 + t * 16 + lg * 4;
      const int chunk = j0 >> 3;
      const int csw = (chunk & ~7) | ((chunk & 7) ^ (ps & 7));
      st4(E + ps * 192 + csw * 8 + (j0 & 7),
          f2b(accA[t][s][0] * rcp2), f2b(accA[t][s][1] * rcp2),
          f2b(accA[t][s][2] * rcp2), f2b(accA[t][s][3] * rcp2));
    }
  }
  #pragma unroll
  for (int j = 0; j < 4; ++j) *(bf8*)(LDS + wLds[j]) = wReg[j];
  BAR();

  // ================= OUT PHASE: y = Wy @ E (K=192, 6 steps) ===============
  f4 acc8[16][2];
  #pragma unroll
  for (int t = 0; t < 16; ++t) { acc8[t][0] = zero4; acc8[t][1] = zero4; }

  #pragma unroll
  for (int q = 0; q < 6; ++q) {
    if (q < 5) {
      #pragma unroll
      for (int j = 0; j < 4; ++j) wReg[j] = *(const bf8*)(wSrc[j] + (q + 1) * 32);
    }
    const int jchunk = q * 4 + lg;
    const int cs0 = (jchunk & ~7) | ((jchunk & 7) ^ (p & 7));
    const bf8 ef0 = *(const bf8*)(E + p * 192 + cs0 * 8);
    const bf8 ef1 = *(const bf8*)(E + (p + 64) * 192 + cs0 * 8);
    #pragma unroll
    for (int t = 0; t < 16; ++t) {
      const int row = t * 16 + l15;
      const int sw = 8 * (lg ^ ((row >> 1) & 3));
      const bf8 wf = *(const bf8*)(LDS + 24576 + row * 32 + sw);
      acc8[t][0] = MFMA(wf, ef0, acc8[t][0]);
      acc8[t][1] = MFMA(wf, ef1, acc8[t][1]);
    }
    BAR();
    if (q < 5) {
      #pragma unroll
      for (int j = 0; j < 4; ++j) *(bf8*)(LDS + wLds[j]) = wReg[j];
      BAR();
    }
  }

  // ================= EPILOGUE: BN + residual + leaky ======================
  const size_t pcol = (size_t)p0g + p;
  #pragma unroll
  for (int t = 0; t < 16; ++t) {
    #pragma unroll
    for (int r = 0; r < 4; ++r) {
      const int c = t * 16 + lg * 4 + r;
      const float sc = scL[c], bi = biL[c];
      const size_t o0 = (((size_t)b * 256 + c) << 13) + pcol;
      const float z0 = x[o0] + acc8[t][0][r] * sc + bi;
      out[o0] = z0 > 0.f ? z0 : 0.2f * z0;
      const size_t o1 = o0 + 64;
      const float z1 = x[o1] + acc8[t][1][r] * sc + bi;
      out[o1] = z1 > 0.f ? z1 : 0.2f * z1;
    }
  }
}

// ---------------------------------------------------------------------------
extern "C" void kernel_launch(void* const* d_in, const int* in_sizes, int n_in,
                              void* d_out, int out_size, void* d_ws, size_t ws_size,
                              hipStream_t stream) {
  const float* x      = (const float*)d_in[0];
  const float* curves = (const float*)d_in[1];
  const float* w_att  = (const float*)d_in[2];
  const float* wa     = (const float*)d_in[3];
  const float* wb     = (const float*)d_in[4];
  const float* wc     = (const float*)d_in[5];
  const float* wn     = (const float*)d_in[6];
  const float* wl     = (const float*)d_in[7];
  const float* wd     = (const float*)d_in[8];
  const float* bng    = (const float*)d_in[9];
  const float* bnb    = (const float*)d_in[10];
  const float* bnm    = (const float*)d_in[11];
  const float* bnv    = (const float*)d_in[12];
  float* out = (float*)d_out;
  float* ws  = (float*)d_ws;

  // f32 map: smi@131072 sma@262144 cinter@393216 cintra@917504 (live -> k_fold)
  // attp@1179648 (4 planes, live k_att -> k_softmax only)
  // W mats (written by k_wfold/2 AFTER k_softmax, overlaying dead attp):
  //   Wac@1179648 Wna@1245184 Wbc@1310720 Wlb@1376256 wdnT@1441792 wdlT@1474560
  // u16 overlays f32 [0,1179648): AnH..Wyp end at u16 2359296 = f32 1179648.
  float* smi    = ws + 131072;
  float* sma    = ws + 262144;
  float* cinter = ws + 393216;
  float* cintra = ws + 917504;
  float* attp   = ws + 1179648;
  float* Wac    = ws + 1179648;
  float* Wna    = ws + 1245184;
  float* Wbc    = ws + 1310720;
  float* Wlb    = ws + 1376256;
  float* wdnT   = ws + 1441792;
  float* wdlT   = ws + 1474560;

  u16* wsb = (u16*)d_ws;
  u16* AnH = wsb;
  u16* AnL = wsb + 524288;
  u16* BlH = wsb + 1048576;
  u16* BlL = wsb + 1310720;
  u16* Wyp = wsb + 1572864;

  k_att    <<<dim3(B_ * 64),  dim3(256), 0, stream>>>(curves, w_att, attp);
  k_softmax<<<dim3(B_),       dim3(256), 0, stream>>>(attp, smi, sma);
  k_wfold  <<<dim3(256),      dim3(256), 0, stream>>>(wd, wn, wl, wdnT, wdlT);
  k_wfold2 <<<dim3(1024),     dim3(256), 0, stream>>>(wa, wb, wc, wdnT, wdlT,
                                                      Wac, Wna, Wbc, Wlb);
  k_agg    <<<dim3(B_ * C_),  dim3(256), 0, stream>>>(curves, smi, sma, cinter, cintra);
  k_fold   <<<dim3(B_ * 24),  dim3(256), 0, stream>>>(cinter, cintra,
                                                      Wac, Wna, Wbc, Wlb,
                                                      AnH, AnL, BlH, BlL, Wyp);
  k_big    <<<dim3(1024),     dim3(256), 0, stream>>>(x, AnH, AnL, BlH, BlL, Wyp,
                                                      bng, bnb, bnm, bnv, out);
}

// Round 18
// 237.569 us; speedup vs baseline: 1.0860x; 1.0106x over previous
//
#include <hip/hip_runtime.h>
#include <hip/hip_bf16.h>
#include <cstdint>

#define B_   16
#define C_   256
#define N_   8192
#define CN_  128
#define CL_  64
#define MID_ 128

typedef unsigned short u16;
typedef __attribute__((ext_vector_type(8))) short bf8;
typedef __attribute__((ext_vector_type(4))) float f4;

#define MFMA(a, bb, c) __builtin_amdgcn_mfma_f32_16x16x32_bf16(a, bb, c, 0, 0, 0)

// LDS-publish barrier without vmcnt drain.
#define BAR() do {                                        \
    __builtin_amdgcn_sched_barrier(0);                    \
    asm volatile("s_waitcnt lgkmcnt(0)" ::: "memory");    \
    __builtin_amdgcn_s_barrier();                         \
    __builtin_amdgcn_sched_barrier(0);                    \
  } while (0)

// 16-byte global -> LDS direct (dest = lds base + lane*16)
__device__ inline void gll16(const void* g, void* l) {
  __builtin_amdgcn_global_load_lds(
      (const __attribute__((address_space(1))) void*)g,
      (__attribute__((address_space(3))) void*)l, 16, 0, 0);
}

__device__ inline u16 f2b(float v) {
  uint32_t b = __builtin_bit_cast(uint32_t, v);
  uint32_t r = (b + 0x7FFFu + ((b >> 16) & 1u)) >> 16;
  return (u16)r;
}
__device__ inline float b2f(u16 u) {
  uint32_t b = ((uint32_t)u) << 16;
  return __builtin_bit_cast(float, b);
}
__device__ inline void st4(u16* p, u16 a, u16 b, u16 c, u16 d) {
  unsigned long long v = (unsigned long long)a | ((unsigned long long)b << 16) |
                         ((unsigned long long)c << 32) | ((unsigned long long)d << 48);
  *(unsigned long long*)p = v;
}

// ---------------------------------------------------------------------------
// K0a: wdnT[m][c] = sum_o wd[c][o]*wn[o][m] ; wdlT[m][c] = sum_o wd[c][128+o]*wl[o][m]
// ---------------------------------------------------------------------------
__global__ __launch_bounds__(256) void k_wfold(const float* __restrict__ wd,
                                               const float* __restrict__ wn,
                                               const float* __restrict__ wl,
                                               float* __restrict__ wdnT,
                                               float* __restrict__ wdlT) {
  const int idx = blockIdx.x * 256 + threadIdx.x;
  const int plane = idx >> 15;
  const int r = idx & 32767;
  const int c = r & 255, m = r >> 8;
  const float* wsrc = plane ? wl : wn;
  const float* wdrow = wd + c * 256 + plane * 128;
  float a0 = 0.f, a1 = 0.f, a2 = 0.f, a3 = 0.f;
  for (int o = 0; o < 128; o += 4) {
    a0 = fmaf(wdrow[o + 0], wsrc[(o + 0) * 128 + m], a0);
    a1 = fmaf(wdrow[o + 1], wsrc[(o + 1) * 128 + m], a1);
    a2 = fmaf(wdrow[o + 2], wsrc[(o + 2) * 128 + m], a2);
    a3 = fmaf(wdrow[o + 3], wsrc[(o + 3) * 128 + m], a3);
  }
  (plane ? wdlT : wdnT)[m * 256 + c] = (a0 + a1) + (a2 + a3);
}

// ---------------------------------------------------------------------------
// K0b: Wac = wa^T@wc   Wna = wa^T@wdnT   Wbc = wb^T@wc   Wlb = wb^T@wdlT
// ---------------------------------------------------------------------------
__global__ __launch_bounds__(256) void k_wfold2(
    const float* __restrict__ wa, const float* __restrict__ wb,
    const float* __restrict__ wc,
    const float* __restrict__ wdnT, const float* __restrict__ wdlT,
    float* __restrict__ Wac, float* __restrict__ Wna,
    float* __restrict__ Wbc, float* __restrict__ Wlb) {
  const int idx = blockIdx.x * 256 + threadIdx.x;
  const int quad = idx >> 16;
  const int r = idx & 65535;
  const int cc = r & 255, c = r >> 8;
  const float* L = (quad & 2) ? wb : wa;
  const float* R = (quad & 1) ? ((quad & 2) ? wdlT : wdnT) : wc;
  float a0 = 0.f, a1 = 0.f, a2 = 0.f, a3 = 0.f;
  for (int m = 0; m < 128; m += 4) {
    a0 = fmaf(L[(m + 0) * 256 + c], R[(m + 0) * 256 + cc], a0);
    a1 = fmaf(L[(m + 1) * 256 + c], R[(m + 1) * 256 + cc], a1);
    a2 = fmaf(L[(m + 2) * 256 + c], R[(m + 2) * 256 + cc], a2);
    a3 = fmaf(L[(m + 3) * 256 + c], R[(m + 3) * 256 + cc], a3);
  }
  float* O = (quad == 0) ? Wac : (quad == 1) ? Wna : (quad == 2) ? Wbc : Wlb;
  O[c * 256 + cc] = (a0 + a1) + (a2 + a3);
}

// ---------------------------------------------------------------------------
// K1: attp over 4 c-quarters; 1024 blocks, float2.
// ---------------------------------------------------------------------------
__global__ __launch_bounds__(256) void k_att(const float* __restrict__ curves,
                                             const float* __restrict__ w_att,
                                             float* __restrict__ attp) {
  const int blk = blockIdx.x;
  const int b = blk >> 6, seg = (blk >> 2) & 15, cs = blk & 3;
  const int e2 = seg * 512 + threadIdx.x * 2;
  const float* cb = curves + (size_t)b * C_ * CN_ * CL_ + (size_t)cs * 64 * 8192 + e2;
  const float* w = w_att + cs * 64;
  float2 a0 = {0.f, 0.f}, a1 = a0, a2 = a0, a3 = a0;
  #pragma unroll 4
  for (int c = 0; c < 64; c += 4) {
    const float w0 = w[c + 0], w1 = w[c + 1], w2 = w[c + 2], w3 = w[c + 3];
    float2 v0 = *(const float2*)&cb[(size_t)(c + 0) * 8192];
    float2 v1 = *(const float2*)&cb[(size_t)(c + 1) * 8192];
    float2 v2 = *(const float2*)&cb[(size_t)(c + 2) * 8192];
    float2 v3 = *(const float2*)&cb[(size_t)(c + 3) * 8192];
    a0.x = fmaf(w0, v0.x, a0.x); a0.y = fmaf(w0, v0.y, a0.y);
    a1.x = fmaf(w1, v1.x, a1.x); a1.y = fmaf(w1, v1.y, a1.y);
    a2.x = fmaf(w2, v2.x, a2.x); a2.y = fmaf(w2, v2.y, a2.y);
    a3.x = fmaf(w3, v3.x, a3.x); a3.y = fmaf(w3, v3.y, a3.y);
  }
  float2 a;
  a.x = (a0.x + a1.x) + (a2.x + a3.x);
  a.y = (a0.y + a1.y) + (a2.y + a3.y);
  *(float2*)&attp[(size_t)(cs * 16 + b) * 8192 + e2] = a;
}

// ---------------------------------------------------------------------------
// K2: dual softmax, sums 4 partial planes on load
// ---------------------------------------------------------------------------
__global__ __launch_bounds__(256) void k_softmax(const float* __restrict__ attp,
                                                 float* __restrict__ smi,
                                                 float* __restrict__ sma) {
  __shared__ float T[CN_ * CL_];
  __shared__ float rmax[CN_], rrcp[CN_], cmax[CL_], crcp[CL_];
  const int b = blockIdx.x;
  const int tid = threadIdx.x;
  for (int idx = tid; idx < CN_ * CL_; idx += 256) {
    T[idx] = attp[(size_t)b * 8192 + idx]
           + attp[(size_t)(16 + b) * 8192 + idx]
           + attp[(size_t)(32 + b) * 8192 + idx]
           + attp[(size_t)(48 + b) * 8192 + idx];
  }
  __syncthreads();
  if (tid < 128) {
    const int n = tid;
    float mx = -1e30f;
    for (int l = 0; l < CL_; ++l) mx = fmaxf(mx, T[n * 64 + l]);
    float s = 0.f;
    for (int l = 0; l < CL_; ++l) s += __expf(T[n * 64 + l] - mx);
    rmax[n] = mx; rrcp[n] = 1.f / s;
  } else if (tid < 192) {
    const int l = tid - 128;
    float mx = -1e30f;
    for (int n = 0; n < CN_; ++n) mx = fmaxf(mx, T[n * 64 + l]);
    float s = 0.f;
    for (int n = 0; n < CN_; ++n) s += __expf(T[n * 64 + l] - mx);
    cmax[l] = mx; crcp[l] = 1.f / s;
  }
  __syncthreads();
  for (int idx = tid; idx < CN_ * CL_; idx += 256) {
    const int n = idx >> 6, l = idx & 63;
    const float v = T[idx];
    smi[b * 8192 + idx] = __expf(v - rmax[n]) * rrcp[n];
    sma[b * 8192 + idx] = __expf(v - cmax[l]) * crcp[l];
  }
}

// ---------------------------------------------------------------------------
// K3: curve aggregation
// ---------------------------------------------------------------------------
__global__ __launch_bounds__(256) void k_agg(const float* __restrict__ curves,
                                             const float* __restrict__ smi,
                                             const float* __restrict__ sma,
                                             float* __restrict__ cinter,
                                             float* __restrict__ cintra) {
  __shared__ float P[CN_ * CL_];
  const int blk = blockIdx.x;
  const int b = blk >> 8, c = blk & 255;
  const int tid = threadIdx.x;
  const float* src = curves + (size_t)(b * 256 + c) * 8192;
  for (int i4 = tid; i4 < 2048; i4 += 256)
    *(float4*)&P[i4 * 4] = *(const float4*)&src[i4 * 4];
  __syncthreads();
  if (tid < 128) {
    const int n = tid;
    const float* sp = smi + (size_t)(b * 128 + n) * 64;
    float a[4] = {0.f, 0.f, 0.f, 0.f};
    for (int l0 = 0; l0 < 64; l0 += 4) {
      float4 pv = *(const float4*)&P[n * 64 + l0];
      float4 sv = *(const float4*)&sp[l0];
      a[0] = fmaf(pv.x, sv.x, a[0]);
      a[1] = fmaf(pv.y, sv.y, a[1]);
      a[2] = fmaf(pv.z, sv.z, a[2]);
      a[3] = fmaf(pv.w, sv.w, a[3]);
    }
    cinter[(size_t)(b * 256 + c) * 128 + n] = (a[0] + a[1]) + (a[2] + a[3]);
  } else if (tid < 192) {
    const int l = tid - 128;
    float a[4] = {0.f, 0.f, 0.f, 0.f};
    for (int n0 = 0; n0 < 128; n0 += 4) {
      a[0] = fmaf(P[(n0 + 0) * 64 + l], sma[(size_t)(b * 128 + n0 + 0) * 64 + l], a[0]);
      a[1] = fmaf(P[(n0 + 1) * 64 + l], sma[(size_t)(b * 128 + n0 + 1) * 64 + l], a[1]);
      a[2] = fmaf(P[(n0 + 2) * 64 + l], sma[(size_t)(b * 128 + n0 + 2) * 64 + l], a[2]);
      a[3] = fmaf(P[(n0 + 3) * 64 + l], sma[(size_t)(b * 128 + n0 + 3) * 64 + l], a[3]);
    }
    cintra[(size_t)(b * 256 + c) * 64 + l] = (a[0] + a[1]) + (a[2] + a[3]);
  }
}

// ---------------------------------------------------------------------------
// K6: fold per batch, K=256 over c from cinter/cintra (round-17 form).
// ---------------------------------------------------------------------------
__global__ __launch_bounds__(256) void k_fold(
    const float* __restrict__ cinter, const float* __restrict__ cintra,
    const float* __restrict__ Wac, const float* __restrict__ Wna,
    const float* __restrict__ Wbc, const float* __restrict__ Wlb,
    u16* __restrict__ AnH, u16* __restrict__ AnL,
    u16* __restrict__ BlH, u16* __restrict__ BlL,
    u16* __restrict__ Wy) {
  __shared__ float S1[64 * 65], S2[64 * 65];
  const int blk = blockIdx.x;
  const int b = blk / 24, tile = blk - b * 24;
  const int tid = threadIdx.x;
  const int r = tid & 63, c4 = tid >> 6;
  float acc[16];
  #pragma unroll
  for (int i = 0; i < 16; ++i) acc[i] = 0.f;

  int n0 = 0, c0 = 0, type;
  if (tile < 8)       { type = 0; n0 = (tile >> 2) * 64; c0 = (tile & 3) * 64; }
  else if (tile < 12) { type = 1; c0 = (tile - 8) * 64; }
  else if (tile < 20) { type = 2; c0 = ((tile - 12) >> 1) * 64; n0 = ((tile - 12) & 1) * 64; }
  else                { type = 3; c0 = (tile - 20) * 64; }

  const float* cib = cinter + (size_t)b * 32768;
  const float* ctb = cintra + (size_t)b * 16384;

  for (int kh = 0; kh < 4; ++kh) {
    __syncthreads();
    if (type == 0) {
      for (int it = 0; it < 16; ++it) {
        const int flat = it * 256 + tid, cl = flat >> 6, j = flat & 63;
        const int c = kh * 64 + cl;
        S1[cl * 65 + j] = Wac[c * 256 + c0 + j];
        S2[cl * 65 + j] = cib[c * 128 + n0 + j];
      }
    } else if (type == 1) {
      for (int it = 0; it < 16; ++it) {
        const int flat = it * 256 + tid, cl = flat >> 6, j = flat & 63;
        const int c = kh * 64 + cl;
        S1[cl * 65 + j] = Wbc[c * 256 + c0 + j];
        S2[cl * 65 + j] = ctb[c * 64 + j];
      }
    } else if (type == 2) {
      for (int it = 0; it < 16; ++it) {
        const int flat = it * 256 + tid, cl = flat >> 6, j = flat & 63;
        const int c = kh * 64 + cl;
        S1[cl * 65 + j] = cib[c * 128 + n0 + j];
        S2[cl * 65 + j] = Wna[c * 256 + c0 + j];
      }
    } else {
      for (int it = 0; it < 16; ++it) {
        const int flat = it * 256 + tid, cl = flat >> 6, j = flat & 63;
        const int c = kh * 64 + cl;
        S1[cl * 65 + j] = ctb[c * 64 + j];
        S2[cl * 65 + j] = Wlb[c * 256 + c0 + j];
      }
    }
    __syncthreads();
    for (int k = 0; k < 64; ++k) {
      const float va = S1[k * 65 + r];
      #pragma unroll
      for (int cc = 0; cc < 16; ++cc)
        acc[cc] = fmaf(va, S2[k * 65 + c4 * 16 + cc], acc[cc]);
    }
  }

  if (type == 0) {
    #pragma unroll
    for (int cc = 0; cc < 16; ++cc) {
      const float v = acc[cc];
      const u16 h = f2b(v);
      const size_t o = (size_t)b * 32768 + (n0 + c4 * 16 + cc) * 256 + c0 + r;
      AnH[o] = h; AnL[o] = f2b(v - b2f(h));
    }
  } else if (type == 1) {
    #pragma unroll
    for (int cc = 0; cc < 16; ++cc) {
      const float v = acc[cc];
      const u16 h = f2b(v);
      const size_t o = (size_t)b * 16384 + (c4 * 16 + cc) * 256 + c0 + r;
      BlH[o] = h; BlL[o] = f2b(v - b2f(h));
    }
  } else if (type == 2) {
    #pragma unroll
    for (int cc = 0; cc < 16; ++cc)
      Wy[(size_t)b * 49152 + (c0 + c4 * 16 + cc) * 192 + n0 + r] = f2b(acc[cc]);
  } else {
    #pragma unroll
    for (int cc = 0; cc < 16; ++cc)
      Wy[(size_t)b * 49152 + (c0 + c4 * 16 + cc) * 192 + 128 + r] = f2b(acc[cc]);
  }
}

// ---------------------------------------------------------------------------
// K7: r15/r17 structure; SINGLE change: A-staging via global_load_lds (16B,
// direct global->LDS, double-buffered). LDS map (u16):
//   Abuf0 hi@0 lo@6144 | Abuf1 hi@12288 lo@18432 (end 24576)
//   X@24576 (4096, end 28672) | E@0 (24576, overlays A after score)
//   Wy@24576 (8192, end 32768, overlays dead X) | scL@32768 biL@33280
// Step: [gll A(q+1)->buf^1 | X(q+2)->regs | compute q | cvt X(q+1)]
//       __syncthreads() (drains gll+reads) ; X(q+1) ds_write ; BAR().
// ---------------------------------------------------------------------------
__global__ __launch_bounds__(256, 2) void k_big(
    const float* __restrict__ x,
    const u16* __restrict__ AnH, const u16* __restrict__ AnL,
    const u16* __restrict__ BlH, const u16* __restrict__ BlL,
    const u16* __restrict__ Wy,
    const float* __restrict__ bng, const float* __restrict__ bnb,
    const float* __restrict__ bnm, const float* __restrict__ bnv,
    float* __restrict__ out) {
  __shared__ __align__(16) u16 LDS[33792];
  float* scL = (float*)(LDS + 32768);
  float* biL = (float*)(LDS + 33280);

  const int tid  = threadIdx.x;
  const int lane = tid & 63;
  const int wid  = tid >> 6;
  const int l15  = lane & 15;
  const int lg   = lane >> 4;
  const int p    = wid * 16 + l15;
  const int blk  = blockIdx.x;
  const int wg   = ((blk & 7) << 7) | (blk >> 3);
  const int b    = wg >> 6;
  const int p0g  = (wg & 63) << 7;
  const f4 zero4 = {0.f, 0.f, 0.f, 0.f};

  const u16* AnHb = AnH + ((size_t)b << 15);
  const u16* AnLb = AnL + ((size_t)b << 15);
  const u16* BlHb = BlH + ((size_t)b << 14);
  const u16* BlLb = BlL + ((size_t)b << 14);
  const u16* Wyb  = Wy  + (size_t)b * 49152;

  {
    const float scv = bng[tid] * rsqrtf(bnv[tid] + 1e-5f);
    scL[tid] = scv;
    biL[tid] = bnb[tid] - bnm[tid] * scv;
  }

  const int xp  = tid & 127;
  const int xkc = tid >> 7;
  const float* xb = x + (size_t)b * C_ * N_ + p0g;
  const int xswp = (xp >> 1) & 3;
  const int xo0 = 24576 + xp * 32 + (((2 * xkc + 0) ^ xswp) * 8);
  const int xo1 = 24576 + xp * 32 + (((2 * xkc + 1) ^ xswp) * 8);

  // A: 6 gll chunks of 16B/thread; byte dest = dbuf*24576 + 16*(j*256+tid)
  const u16* aSrc[6];
  #pragma unroll
  for (int j = 0; j < 6; ++j) {
    const int cid = j * 256 + tid;
    const int plane = (cid >= 768) ? 1 : 0;
    const int rr = cid - plane * 768;
    const int row = rr >> 2, kc = rr & 3;
    const u16* base;
    if (row < 128) base = (plane ? AnLb : AnHb) + row * 256;
    else           base = (plane ? BlLb : BlHb) + (row - 128) * 256;
    aSrc[j] = base + 8 * (kc ^ ((row >> 1) & 3));
  }
  // wave-uniform LDS bases for gll (u16 units: 8*(j*256 + wid*64))
  int aDstW[6];
  #pragma unroll
  for (int j = 0; j < 6; ++j) aDstW[j] = 8 * (j * 256 + wid * 64);

  const u16* wSrc[4];
  int wLds[4];
  #pragma unroll
  for (int j = 0; j < 4; ++j) {
    const int cid = j * 256 + tid;
    const int row = cid >> 2, kc = cid & 3;
    wSrc[j] = Wyb + row * 192 + 8 * (kc ^ ((row >> 1) & 3));
    wLds[j] = 24576 + row * 32 + kc * 8;
  }

  // ================= SCORE PHASE =================
  f4 accS[8][2], accA[4][2];
  #pragma unroll
  for (int t = 0; t < 8; ++t) { accS[t][0] = zero4; accS[t][1] = zero4; }
  #pragma unroll
  for (int t = 0; t < 4; ++t) { accA[t][0] = zero4; accA[t][1] = zero4; }

  float xRaw[2][16];

  // prologue: gll A(0)->buf0; X(0) reg->cvt->write; issue X(1)
  #pragma unroll
  for (int j = 0; j < 6; ++j) gll16(aSrc[j], LDS + aDstW[j]);
  #pragma unroll
  for (int jj = 0; jj < 16; ++jj)
    xRaw[0][jj] = xb[(size_t)(xkc * 16 + jj) * N_ + xp];
  {
    bf8 h0, h1;
    #pragma unroll
    for (int jj = 0; jj < 8; ++jj) {
      h0[jj] = (short)f2b(xRaw[0][jj]);
      h1[jj] = (short)f2b(xRaw[0][8 + jj]);
    }
    *(bf8*)(LDS + xo0) = h0;
    *(bf8*)(LDS + xo1) = h1;
  }
  #pragma unroll
  for (int jj = 0; jj < 16; ++jj)
    xRaw[1][jj] = xb[(size_t)(32 + xkc * 16 + jj) * N_ + xp];
  __syncthreads();            // A(0) landed + X(0) visible

  const int rswp = (p >> 1) & 3;
  #pragma unroll
  for (int q = 0; q < 8; ++q) {
    const int cbuf = (q & 1) * 12288;           // compute buffer base (u16)
    if (q < 7) {                                 // gll A(q+1) -> other buffer
      const int nbuf = ((q + 1) & 1) * 12288;
      #pragma unroll
      for (int j = 0; j < 6; ++j)
        gll16(aSrc[j] + (q + 1) * 32, LDS + nbuf + aDstW[j]);
    }
    if (q < 6) {
      #pragma unroll
      for (int jj = 0; jj < 16; ++jj)
        xRaw[q & 1][jj] = xb[(size_t)((q + 2) * 32 + xkc * 16 + jj) * N_ + xp];
    }
    const bf8 xh0 = *(const bf8*)(LDS + 24576 + p * 32 + ((lg ^ rswp) * 8));
    const bf8 xh1 = *(const bf8*)(LDS + 24576 + (p + 64) * 32 + ((lg ^ rswp) * 8));
    #pragma unroll
    for (int t = 0; t < 8; ++t) {
      const int row = t * 16 + l15;
      const int sw = 8 * (lg ^ ((row >> 1) & 3));
      const bf8 ah = *(const bf8*)(LDS + cbuf + row * 32 + sw);
      const bf8 al = *(const bf8*)(LDS + cbuf + 6144 + row * 32 + sw);
      accS[t][0] = MFMA(ah, xh0, accS[t][0]);
      accS[t][0] = MFMA(al, xh0, accS[t][0]);
      accS[t][1] = MFMA(ah, xh1, accS[t][1]);
      accS[t][1] = MFMA(al, xh1, accS[t][1]);
    }
    #pragma unroll
    for (int t = 0; t < 4; ++t) {
      const int row = 128 + t * 16 + l15;
      const int sw = 8 * (lg ^ ((row >> 1) & 3));
      const bf8 ah = *(const bf8*)(LDS + cbuf + row * 32 + sw);
      const bf8 al = *(const bf8*)(LDS + cbuf + 6144 + row * 32 + sw);
      accA[t][0] = MFMA(ah, xh0, accA[t][0]);
      accA[t][0] = MFMA(al, xh0, accA[t][0]);
      accA[t][1] = MFMA(ah, xh1, accA[t][1]);
      accA[t][1] = MFMA(al, xh1, accA[t][1]);
    }
    bf8 nh0, nh1;
    if (q < 7) {
      #pragma unroll
      for (int jj = 0; jj < 8; ++jj) {
        nh0[jj] = (short)f2b(xRaw[(q + 1) & 1][jj]);
        nh1[jj] = (short)f2b(xRaw[(q + 1) & 1][8 + jj]);
      }
    }
    __syncthreads();          // drains gll A(q+1) + all reads of tile q
    if (q < 7) {
      *(bf8*)(LDS + xo0) = nh0;
      *(bf8*)(LDS + xo1) = nh1;
      BAR();                  // X(q+1) visible
    }
  }

  // ================= SOFTMAX + E + Wy(0) =================
  bf8 wReg[4];
  #pragma unroll
  for (int j = 0; j < 4; ++j) wReg[j] = *(const bf8*)(wSrc[j]);

  u16* E = LDS;   // [128 p][192 j], chunk-XOR by (p&7); overlays dead A dbuf
  #pragma unroll
  for (int s = 0; s < 2; ++s) {
    const int ps = p + s * 64;
    float mx = -3.0e38f;
    #pragma unroll
    for (int t = 0; t < 8; ++t)
      #pragma unroll
      for (int r = 0; r < 4; ++r) mx = fmaxf(mx, accS[t][s][r]);
    mx = fmaxf(mx, __shfl_xor(mx, 16));
    mx = fmaxf(mx, __shfl_xor(mx, 32));
    float sum = 0.f;
    #pragma unroll
    for (int t = 0; t < 8; ++t)
      #pragma unroll
      for (int r = 0; r < 4; ++r) {
        const float e = __expf(accS[t][s][r] - mx);
        accS[t][s][r] = e; sum += e;
      }
    sum += __shfl_xor(sum, 16);
    sum += __shfl_xor(sum, 32);
    const float rcp = 1.f / sum;
    #pragma unroll
    for (int t = 0; t < 8; ++t) {
      const int j0 = t * 16 + lg * 4;
      const int chunk = j0 >> 3;
      const int csw = (chunk & ~7) | ((chunk & 7) ^ (ps & 7));
      st4(E + ps * 192 + csw * 8 + (j0 & 7),
          f2b(accS[t][s][0] * rcp), f2b(accS[t][s][1] * rcp),
          f2b(accS[t][s][2] * rcp), f2b(accS[t][s][3] * rcp));
    }
    float mx2 = -3.0e38f;
    #pragma unroll
    for (int t = 0; t < 4; ++t)
      #pragma unroll
      for (int r = 0; r < 4; ++r) mx2 = fmaxf(mx2, accA[t][s][r]);
    mx2 = fmaxf(mx2, __shfl_xor(mx2, 16));
    mx2 = fmaxf(mx2, __shfl_xor(mx2, 32));
    float sum2 = 0.f;
    #pragma unroll
    for (int t = 0; t < 4; ++t)
      #pragma unroll
      for (int r = 0; r < 4; ++r) {
        const float e = __expf(accA[t][s][r] - mx2);
        accA[t][s][r] = e; sum2 += e;
      }
    sum2 += __shfl_xor(sum2, 16);
    sum2 += __shfl_xor(sum2, 32);
    const float rcp2 = 1.f / sum2;
    #pragma unroll
    for (int t = 0; t < 4; ++t) {
      const int j0 = 128 + t * 16 + lg * 4;
      const int chunk = j0 >> 3;
      const int csw = (chunk & ~7) | ((chunk & 7) ^ (ps & 7));
      st4(E + ps * 192 + csw * 8 + (j0 & 7),
          f2b(accA[t][s][0] * rcp2), f2b(accA[t][s][1] * rcp2),
          f2b(accA[t][s][2] * rcp2), f2b(accA[t][s][3] * rcp2));
    }
  }
  #pragma unroll
  for (int j = 0; j < 4; ++j) *(bf8*)(LDS + wLds[j]) = wReg[j];
  BAR();                      // E + Wy(0) visible

  // ================= OUT PHASE: y = Wy @ E (K=192, 6 steps) ===============
  f4 acc8[16][2];
  #pragma unroll
  for (int t = 0; t < 16; ++t) { acc8[t][0] = zero4; acc8[t][1] = zero4; }

  #pragma unroll
  for (int q = 0; q < 6; ++q) {
    if (q < 5) {
      #pragma unroll
      for (int j = 0; j < 4; ++j) wReg[j] = *(const bf8*)(wSrc[j] + (q + 1) * 32);
    }
    const int jchunk = q * 4 + lg;
    const int cs0 = (jchunk & ~7) | ((jchunk & 7) ^ (p & 7));
    const bf8 ef0 = *(const bf8*)(E + p * 192 + cs0 * 8);
    const bf8 ef1 = *(const bf8*)(E + (p + 64) * 192 + cs0 * 8);
    #pragma unroll
    for (int t = 0; t < 16; ++t) {
      const int row = t * 16 + l15;
      const int sw = 8 * (lg ^ ((row >> 1) & 3));
      const bf8 wf = *(const bf8*)(LDS + 24576 + row * 32 + sw);
      acc8[t][0] = MFMA(wf, ef0, acc8[t][0]);
      acc8[t][1] = MFMA(wf, ef1, acc8[t][1]);
    }
    BAR();
    if (q < 5) {
      #pragma unroll
      for (int j = 0; j < 4; ++j) *(bf8*)(LDS + wLds[j]) = wReg[j];
      BAR();
    }
  }

  // ================= EPILOGUE: BN + residual + leaky ======================
  const size_t pcol = (size_t)p0g + p;
  #pragma unroll
  for (int t = 0; t < 16; ++t) {
    #pragma unroll
    for (int r = 0; r < 4; ++r) {
      const int c = t * 16 + lg * 4 + r;
      const float sc = scL[c], bi = biL[c];
      const size_t o0 = (((size_t)b * 256 + c) << 13) + pcol;
      const float z0 = x[o0] + acc8[t][0][r] * sc + bi;
      out[o0] = z0 > 0.f ? z0 : 0.2f * z0;
      const size_t o1 = o0 + 64;
      const float z1 = x[o1] + acc8[t][1][r] * sc + bi;
      out[o1] = z1 > 0.f ? z1 : 0.2f * z1;
    }
  }
}

// ---------------------------------------------------------------------------
extern "C" void kernel_launch(void* const* d_in, const int* in_sizes, int n_in,
                              void* d_out, int out_size, void* d_ws, size_t ws_size,
                              hipStream_t stream) {
  const float* x      = (const float*)d_in[0];
  const float* curves = (const float*)d_in[1];
  const float* w_att  = (const float*)d_in[2];
  const float* wa     = (const float*)d_in[3];
  const float* wb     = (const float*)d_in[4];
  const float* wc     = (const float*)d_in[5];
  const float* wn     = (const float*)d_in[6];
  const float* wl     = (const float*)d_in[7];
  const float* wd     = (const float*)d_in[8];
  const float* bng    = (const float*)d_in[9];
  const float* bnb    = (const float*)d_in[10];
  const float* bnm    = (const float*)d_in[11];
  const float* bnv    = (const float*)d_in[12];
  float* out = (float*)d_out;
  float* ws  = (float*)d_ws;

  float* smi    = ws + 131072;
  float* sma    = ws + 262144;
  float* cinter = ws + 393216;
  float* cintra = ws + 917504;
  float* attp   = ws + 1179648;
  float* Wac    = ws + 1179648;
  float* Wna    = ws + 1245184;
  float* Wbc    = ws + 1310720;
  float* Wlb    = ws + 1376256;
  float* wdnT   = ws + 1441792;
  float* wdlT   = ws + 1474560;

  u16* wsb = (u16*)d_ws;
  u16* AnH = wsb;
  u16* AnL = wsb + 524288;
  u16* BlH = wsb + 1048576;
  u16* BlL = wsb + 1310720;
  u16* Wyp = wsb + 1572864;

  k_att    <<<dim3(B_ * 64),  dim3(256), 0, stream>>>(curves, w_att, attp);
  k_softmax<<<dim3(B_),       dim3(256), 0, stream>>>(attp, smi, sma);
  k_wfold  <<<dim3(256),      dim3(256), 0, stream>>>(wd, wn, wl, wdnT, wdlT);
  k_wfold2 <<<dim3(1024),     dim3(256), 0, stream>>>(wa, wb, wc, wdnT, wdlT,
                                                      Wac, Wna, Wbc, Wlb);
  k_agg    <<<dim3(B_ * C_),  dim3(256), 0, stream>>>(curves, smi, sma, cinter, cintra);
  k_fold   <<<dim3(B_ * 24),  dim3(256), 0, stream>>>(cinter, cintra,
                                                      Wac, Wna, Wbc, Wlb,
                                                      AnH, AnL, BlH, BlL, Wyp);
  k_big    <<<dim3(1024),     dim3(256), 0, stream>>>(x, AnH, AnL, BlH, BlL, Wyp,
                                                      bng, bnb, bnm, bnv, out);
}

// Round 19
// 224.248 us; speedup vs baseline: 1.1505x; 1.0594x over previous
//
#include <hip/hip_runtime.h>
#include <hip/hip_bf16.h>
#include <cstdint>

#define B_   16
#define C_   256
#define N_   8192
#define CN_  128
#define CL_  64
#define MID_ 128

typedef unsigned short u16;
typedef __attribute__((ext_vector_type(8))) short bf8;
typedef __attribute__((ext_vector_type(4))) float f4;

#define MFMA(a, bb, c) __builtin_amdgcn_mfma_f32_16x16x32_bf16(a, bb, c, 0, 0, 0)

// LDS-publish barrier without vmcnt drain.
#define BAR() do {                                        \
    __builtin_amdgcn_sched_barrier(0);                    \
    asm volatile("s_waitcnt lgkmcnt(0)" ::: "memory");    \
    __builtin_amdgcn_s_barrier();                         \
    __builtin_amdgcn_sched_barrier(0);                    \
  } while (0)

// 16-byte global -> LDS direct (dest = lds base + lane*16)
__device__ inline void gll16(const void* g, void* l) {
  __builtin_amdgcn_global_load_lds(
      (const __attribute__((address_space(1))) void*)g,
      (__attribute__((address_space(3))) void*)l, 16, 0, 0);
}

__device__ inline u16 f2b(float v) {
  uint32_t b = __builtin_bit_cast(uint32_t, v);
  uint32_t r = (b + 0x7FFFu + ((b >> 16) & 1u)) >> 16;
  return (u16)r;
}
__device__ inline float b2f(u16 u) {
  uint32_t b = ((uint32_t)u) << 16;
  return __builtin_bit_cast(float, b);
}
__device__ inline void st4(u16* p, u16 a, u16 b, u16 c, u16 d) {
  unsigned long long v = (unsigned long long)a | ((unsigned long long)b << 16) |
                         ((unsigned long long)c << 32) | ((unsigned long long)d << 48);
  *(unsigned long long*)p = v;
}

// ---------------------------------------------------------------------------
// K1 (merged): blocks [0, wf_base): k_att (attp partial planes).
//              blocks [wf_base, ...): k_wfold (wdnT/wdlT).
// ---------------------------------------------------------------------------
__global__ __launch_bounds__(256) void k_att_wf(
    const float* __restrict__ curves, const float* __restrict__ w_att,
    float* __restrict__ attp,
    const float* __restrict__ wd, const float* __restrict__ wn,
    const float* __restrict__ wl,
    float* __restrict__ wdnT, float* __restrict__ wdlT, int wf_base) {
  const int bx = blockIdx.x;
  if (bx < wf_base) {
    const int blk = bx;
    const int b = blk >> 6, seg = (blk >> 2) & 15, cs = blk & 3;
    const int e2 = seg * 512 + threadIdx.x * 2;
    const float* cb = curves + (size_t)b * C_ * CN_ * CL_ + (size_t)cs * 64 * 8192 + e2;
    const float* w = w_att + cs * 64;
    float2 a0 = {0.f, 0.f}, a1 = a0, a2 = a0, a3 = a0;
    #pragma unroll 4
    for (int c = 0; c < 64; c += 4) {
      const float w0 = w[c + 0], w1 = w[c + 1], w2 = w[c + 2], w3 = w[c + 3];
      float2 v0 = *(const float2*)&cb[(size_t)(c + 0) * 8192];
      float2 v1 = *(const float2*)&cb[(size_t)(c + 1) * 8192];
      float2 v2 = *(const float2*)&cb[(size_t)(c + 2) * 8192];
      float2 v3 = *(const float2*)&cb[(size_t)(c + 3) * 8192];
      a0.x = fmaf(w0, v0.x, a0.x); a0.y = fmaf(w0, v0.y, a0.y);
      a1.x = fmaf(w1, v1.x, a1.x); a1.y = fmaf(w1, v1.y, a1.y);
      a2.x = fmaf(w2, v2.x, a2.x); a2.y = fmaf(w2, v2.y, a2.y);
      a3.x = fmaf(w3, v3.x, a3.x); a3.y = fmaf(w3, v3.y, a3.y);
    }
    float2 a;
    a.x = (a0.x + a1.x) + (a2.x + a3.x);
    a.y = (a0.y + a1.y) + (a2.y + a3.y);
    *(float2*)&attp[(size_t)(cs * 16 + b) * 8192 + e2] = a;
  } else {
    const int idx = (bx - wf_base) * 256 + threadIdx.x;
    const int plane = idx >> 15;
    const int r = idx & 32767;
    const int c = r & 255, m = r >> 8;
    const float* wsrc = plane ? wl : wn;
    const float* wdrow = wd + c * 256 + plane * 128;
    float a0 = 0.f, a1 = 0.f, a2 = 0.f, a3 = 0.f;
    for (int o = 0; o < 128; o += 4) {
      a0 = fmaf(wdrow[o + 0], wsrc[(o + 0) * 128 + m], a0);
      a1 = fmaf(wdrow[o + 1], wsrc[(o + 1) * 128 + m], a1);
      a2 = fmaf(wdrow[o + 2], wsrc[(o + 2) * 128 + m], a2);
      a3 = fmaf(wdrow[o + 3], wsrc[(o + 3) * 128 + m], a3);
    }
    (plane ? wdlT : wdnT)[m * 256 + c] = (a0 + a1) + (a2 + a3);
  }
}

// ---------------------------------------------------------------------------
// K2 (merged): blocks [0, sm_cnt): dual softmax (4 partial planes summed).
//              blocks [sm_cnt, ...): k_wfold2 (Wac/Wna/Wbc/Wlb).
// ---------------------------------------------------------------------------
__global__ __launch_bounds__(256) void k_sm_wf2(
    const float* __restrict__ attp, float* __restrict__ smi,
    float* __restrict__ sma,
    const float* __restrict__ wa, const float* __restrict__ wb,
    const float* __restrict__ wc,
    const float* __restrict__ wdnT, const float* __restrict__ wdlT,
    float* __restrict__ Wac, float* __restrict__ Wna,
    float* __restrict__ Wbc, float* __restrict__ Wlb, int sm_cnt) {
  const int bx = blockIdx.x;
  if (bx < sm_cnt) {
    __shared__ float T[CN_ * CL_];
    __shared__ float rmax[CN_], rrcp[CN_], cmax[CL_], crcp[CL_];
    const int b = bx;
    const int tid = threadIdx.x;
    for (int idx = tid; idx < CN_ * CL_; idx += 256) {
      T[idx] = attp[(size_t)b * 8192 + idx]
             + attp[(size_t)(16 + b) * 8192 + idx]
             + attp[(size_t)(32 + b) * 8192 + idx]
             + attp[(size_t)(48 + b) * 8192 + idx];
    }
    __syncthreads();
    if (tid < 128) {
      const int n = tid;
      float mx = -1e30f;
      for (int l = 0; l < CL_; ++l) mx = fmaxf(mx, T[n * 64 + l]);
      float s = 0.f;
      for (int l = 0; l < CL_; ++l) s += __expf(T[n * 64 + l] - mx);
      rmax[n] = mx; rrcp[n] = 1.f / s;
    } else if (tid < 192) {
      const int l = tid - 128;
      float mx = -1e30f;
      for (int n = 0; n < CN_; ++n) mx = fmaxf(mx, T[n * 64 + l]);
      float s = 0.f;
      for (int n = 0; n < CN_; ++n) s += __expf(T[n * 64 + l] - mx);
      cmax[l] = mx; crcp[l] = 1.f / s;
    }
    __syncthreads();
    for (int idx = tid; idx < CN_ * CL_; idx += 256) {
      const int n = idx >> 6, l = idx & 63;
      const float v = T[idx];
      smi[b * 8192 + idx] = __expf(v - rmax[n]) * rrcp[n];
      sma[b * 8192 + idx] = __expf(v - cmax[l]) * crcp[l];
    }
  } else {
    const int idx = (bx - sm_cnt) * 256 + threadIdx.x;
    const int quad = idx >> 16;
    const int r = idx & 65535;
    const int cc = r & 255, c = r >> 8;
    const float* L = (quad & 2) ? wb : wa;
    const float* R = (quad & 1) ? ((quad & 2) ? wdlT : wdnT) : wc;
    float a0 = 0.f, a1 = 0.f, a2 = 0.f, a3 = 0.f;
    for (int m = 0; m < 128; m += 4) {
      a0 = fmaf(L[(m + 0) * 256 + c], R[(m + 0) * 256 + cc], a0);
      a1 = fmaf(L[(m + 1) * 256 + c], R[(m + 1) * 256 + cc], a1);
      a2 = fmaf(L[(m + 2) * 256 + c], R[(m + 2) * 256 + cc], a2);
      a3 = fmaf(L[(m + 3) * 256 + c], R[(m + 3) * 256 + cc], a3);
    }
    float* O = (quad == 0) ? Wac : (quad == 1) ? Wna : (quad == 2) ? Wbc : Wlb;
    O[c * 256 + cc] = (a0 + a1) + (a2 + a3);
  }
}

// ---------------------------------------------------------------------------
// K3: curve aggregation (unchanged)
// ---------------------------------------------------------------------------
__global__ __launch_bounds__(256) void k_agg(const float* __restrict__ curves,
                                             const float* __restrict__ smi,
                                             const float* __restrict__ sma,
                                             float* __restrict__ cinter,
                                             float* __restrict__ cintra) {
  __shared__ float P[CN_ * CL_];
  const int blk = blockIdx.x;
  const int b = blk >> 8, c = blk & 255;
  const int tid = threadIdx.x;
  const float* src = curves + (size_t)(b * 256 + c) * 8192;
  for (int i4 = tid; i4 < 2048; i4 += 256)
    *(float4*)&P[i4 * 4] = *(const float4*)&src[i4 * 4];
  __syncthreads();
  if (tid < 128) {
    const int n = tid;
    const float* sp = smi + (size_t)(b * 128 + n) * 64;
    float a[4] = {0.f, 0.f, 0.f, 0.f};
    for (int l0 = 0; l0 < 64; l0 += 4) {
      float4 pv = *(const float4*)&P[n * 64 + l0];
      float4 sv = *(const float4*)&sp[l0];
      a[0] = fmaf(pv.x, sv.x, a[0]);
      a[1] = fmaf(pv.y, sv.y, a[1]);
      a[2] = fmaf(pv.z, sv.z, a[2]);
      a[3] = fmaf(pv.w, sv.w, a[3]);
    }
    cinter[(size_t)(b * 256 + c) * 128 + n] = (a[0] + a[1]) + (a[2] + a[3]);
  } else if (tid < 192) {
    const int l = tid - 128;
    float a[4] = {0.f, 0.f, 0.f, 0.f};
    for (int n0 = 0; n0 < 128; n0 += 4) {
      a[0] = fmaf(P[(n0 + 0) * 64 + l], sma[(size_t)(b * 128 + n0 + 0) * 64 + l], a[0]);
      a[1] = fmaf(P[(n0 + 1) * 64 + l], sma[(size_t)(b * 128 + n0 + 1) * 64 + l], a[1]);
      a[2] = fmaf(P[(n0 + 2) * 64 + l], sma[(size_t)(b * 128 + n0 + 2) * 64 + l], a[2]);
      a[3] = fmaf(P[(n0 + 3) * 64 + l], sma[(size_t)(b * 128 + n0 + 3) * 64 + l], a[3]);
    }
    cintra[(size_t)(b * 256 + c) * 64 + l] = (a[0] + a[1]) + (a[2] + a[3]);
  }
}

// ---------------------------------------------------------------------------
// K4: fold per batch, K=256 over c from cinter/cintra (unchanged logic).
// ---------------------------------------------------------------------------
__global__ __launch_bounds__(256) void k_fold(
    const float* __restrict__ cinter, const float* __restrict__ cintra,
    const float* __restrict__ Wac, const float* __restrict__ Wna,
    const float* __restrict__ Wbc, const float* __restrict__ Wlb,
    u16* __restrict__ AnH, u16* __restrict__ AnL,
    u16* __restrict__ BlH, u16* __restrict__ BlL,
    u16* __restrict__ Wy) {
  __shared__ float S1[64 * 65], S2[64 * 65];
  const int blk = blockIdx.x;
  const int b = blk / 24, tile = blk - b * 24;
  const int tid = threadIdx.x;
  const int r = tid & 63, c4 = tid >> 6;
  float acc[16];
  #pragma unroll
  for (int i = 0; i < 16; ++i) acc[i] = 0.f;

  int n0 = 0, c0 = 0, type;
  if (tile < 8)       { type = 0; n0 = (tile >> 2) * 64; c0 = (tile & 3) * 64; }
  else if (tile < 12) { type = 1; c0 = (tile - 8) * 64; }
  else if (tile < 20) { type = 2; c0 = ((tile - 12) >> 1) * 64; n0 = ((tile - 12) & 1) * 64; }
  else                { type = 3; c0 = (tile - 20) * 64; }

  const float* cib = cinter + (size_t)b * 32768;
  const float* ctb = cintra + (size_t)b * 16384;

  for (int kh = 0; kh < 4; ++kh) {
    __syncthreads();
    if (type == 0) {
      for (int it = 0; it < 16; ++it) {
        const int flat = it * 256 + tid, cl = flat >> 6, j = flat & 63;
        const int c = kh * 64 + cl;
        S1[cl * 65 + j] = Wac[c * 256 + c0 + j];
        S2[cl * 65 + j] = cib[c * 128 + n0 + j];
      }
    } else if (type == 1) {
      for (int it = 0; it < 16; ++it) {
        const int flat = it * 256 + tid, cl = flat >> 6, j = flat & 63;
        const int c = kh * 64 + cl;
        S1[cl * 65 + j] = Wbc[c * 256 + c0 + j];
        S2[cl * 65 + j] = ctb[c * 64 + j];
      }
    } else if (type == 2) {
      for (int it = 0; it < 16; ++it) {
        const int flat = it * 256 + tid, cl = flat >> 6, j = flat & 63;
        const int c = kh * 64 + cl;
        S1[cl * 65 + j] = cib[c * 128 + n0 + j];
        S2[cl * 65 + j] = Wna[c * 256 + c0 + j];
      }
    } else {
      for (int it = 0; it < 16; ++it) {
        const int flat = it * 256 + tid, cl = flat >> 6, j = flat & 63;
        const int c = kh * 64 + cl;
        S1[cl * 65 + j] = ctb[c * 64 + j];
        S2[cl * 65 + j] = Wlb[c * 256 + c0 + j];
      }
    }
    __syncthreads();
    for (int k = 0; k < 64; ++k) {
      const float va = S1[k * 65 + r];
      #pragma unroll
      for (int cc = 0; cc < 16; ++cc)
        acc[cc] = fmaf(va, S2[k * 65 + c4 * 16 + cc], acc[cc]);
    }
  }

  if (type == 0) {
    #pragma unroll
    for (int cc = 0; cc < 16; ++cc) {
      const float v = acc[cc];
      const u16 h = f2b(v);
      const size_t o = (size_t)b * 32768 + (n0 + c4 * 16 + cc) * 256 + c0 + r;
      AnH[o] = h; AnL[o] = f2b(v - b2f(h));
    }
  } else if (type == 1) {
    #pragma unroll
    for (int cc = 0; cc < 16; ++cc) {
      const float v = acc[cc];
      const u16 h = f2b(v);
      const size_t o = (size_t)b * 16384 + (c4 * 16 + cc) * 256 + c0 + r;
      BlH[o] = h; BlL[o] = f2b(v - b2f(h));
    }
  } else if (type == 2) {
    #pragma unroll
    for (int cc = 0; cc < 16; ++cc)
      Wy[(size_t)b * 49152 + (c0 + c4 * 16 + cc) * 192 + n0 + r] = f2b(acc[cc]);
  } else {
    #pragma unroll
    for (int cc = 0; cc < 16; ++cc)
      Wy[(size_t)b * 49152 + (c0 + c4 * 16 + cc) * 192 + 128 + r] = f2b(acc[cc]);
  }
}

// ---------------------------------------------------------------------------
// K5: k_big — r18 verbatim (gll A-staging, X bf16, p-tile 128, 66 KB LDS).
// ---------------------------------------------------------------------------
__global__ __launch_bounds__(256, 2) void k_big(
    const float* __restrict__ x,
    const u16* __restrict__ AnH, const u16* __restrict__ AnL,
    const u16* __restrict__ BlH, const u16* __restrict__ BlL,
    const u16* __restrict__ Wy,
    const float* __restrict__ bng, const float* __restrict__ bnb,
    const float* __restrict__ bnm, const float* __restrict__ bnv,
    float* __restrict__ out) {
  __shared__ __align__(16) u16 LDS[33792];
  float* scL = (float*)(LDS + 32768);
  float* biL = (float*)(LDS + 33280);

  const int tid  = threadIdx.x;
  const int lane = tid & 63;
  const int wid  = tid >> 6;
  const int l15  = lane & 15;
  const int lg   = lane >> 4;
  const int p    = wid * 16 + l15;
  const int blk  = blockIdx.x;
  const int wg   = ((blk & 7) << 7) | (blk >> 3);
  const int b    = wg >> 6;
  const int p0g  = (wg & 63) << 7;
  const f4 zero4 = {0.f, 0.f, 0.f, 0.f};

  const u16* AnHb = AnH + ((size_t)b << 15);
  const u16* AnLb = AnL + ((size_t)b << 15);
  const u16* BlHb = BlH + ((size_t)b << 14);
  const u16* BlLb = BlL + ((size_t)b << 14);
  const u16* Wyb  = Wy  + (size_t)b * 49152;

  {
    const float scv = bng[tid] * rsqrtf(bnv[tid] + 1e-5f);
    scL[tid] = scv;
    biL[tid] = bnb[tid] - bnm[tid] * scv;
  }

  const int xp  = tid & 127;
  const int xkc = tid >> 7;
  const float* xb = x + (size_t)b * C_ * N_ + p0g;
  const int xswp = (xp >> 1) & 3;
  const int xo0 = 24576 + xp * 32 + (((2 * xkc + 0) ^ xswp) * 8);
  const int xo1 = 24576 + xp * 32 + (((2 * xkc + 1) ^ xswp) * 8);

  const u16* aSrc[6];
  #pragma unroll
  for (int j = 0; j < 6; ++j) {
    const int cid = j * 256 + tid;
    const int plane = (cid >= 768) ? 1 : 0;
    const int rr = cid - plane * 768;
    const int row = rr >> 2, kc = rr & 3;
    const u16* base;
    if (row < 128) base = (plane ? AnLb : AnHb) + row * 256;
    else           base = (plane ? BlLb : BlHb) + (row - 128) * 256;
    aSrc[j] = base + 8 * (kc ^ ((row >> 1) & 3));
  }
  int aDstW[6];
  #pragma unroll
  for (int j = 0; j < 6; ++j) aDstW[j] = 8 * (j * 256 + wid * 64);

  const u16* wSrc[4];
  int wLds[4];
  #pragma unroll
  for (int j = 0; j < 4; ++j) {
    const int cid = j * 256 + tid;
    const int row = cid >> 2, kc = cid & 3;
    wSrc[j] = Wyb + row * 192 + 8 * (kc ^ ((row >> 1) & 3));
    wLds[j] = 24576 + row * 32 + kc * 8;
  }

  // ================= SCORE PHASE =================
  f4 accS[8][2], accA[4][2];
  #pragma unroll
  for (int t = 0; t < 8; ++t) { accS[t][0] = zero4; accS[t][1] = zero4; }
  #pragma unroll
  for (int t = 0; t < 4; ++t) { accA[t][0] = zero4; accA[t][1] = zero4; }

  float xRaw[2][16];

  #pragma unroll
  for (int j = 0; j < 6; ++j) gll16(aSrc[j], LDS + aDstW[j]);
  #pragma unroll
  for (int jj = 0; jj < 16; ++jj)
    xRaw[0][jj] = xb[(size_t)(xkc * 16 + jj) * N_ + xp];
  {
    bf8 h0, h1;
    #pragma unroll
    for (int jj = 0; jj < 8; ++jj) {
      h0[jj] = (short)f2b(xRaw[0][jj]);
      h1[jj] = (short)f2b(xRaw[0][8 + jj]);
    }
    *(bf8*)(LDS + xo0) = h0;
    *(bf8*)(LDS + xo1) = h1;
  }
  #pragma unroll
  for (int jj = 0; jj < 16; ++jj)
    xRaw[1][jj] = xb[(size_t)(32 + xkc * 16 + jj) * N_ + xp];
  __syncthreads();

  const int rswp = (p >> 1) & 3;
  #pragma unroll
  for (int q = 0; q < 8; ++q) {
    const int cbuf = (q & 1) * 12288;
    if (q < 7) {
      const int nbuf = ((q + 1) & 1) * 12288;
      #pragma unroll
      for (int j = 0; j < 6; ++j)
        gll16(aSrc[j] + (q + 1) * 32, LDS + nbuf + aDstW[j]);
    }
    if (q < 6) {
      #pragma unroll
      for (int jj = 0; jj < 16; ++jj)
        xRaw[q & 1][jj] = xb[(size_t)((q + 2) * 32 + xkc * 16 + jj) * N_ + xp];
    }
    const bf8 xh0 = *(const bf8*)(LDS + 24576 + p * 32 + ((lg ^ rswp) * 8));
    const bf8 xh1 = *(const bf8*)(LDS + 24576 + (p + 64) * 32 + ((lg ^ rswp) * 8));
    #pragma unroll
    for (int t = 0; t < 8; ++t) {
      const int row = t * 16 + l15;
      const int sw = 8 * (lg ^ ((row >> 1) & 3));
      const bf8 ah = *(const bf8*)(LDS + cbuf + row * 32 + sw);
      const bf8 al = *(const bf8*)(LDS + cbuf + 6144 + row * 32 + sw);
      accS[t][0] = MFMA(ah, xh0, accS[t][0]);
      accS[t][0] = MFMA(al, xh0, accS[t][0]);
      accS[t][1] = MFMA(ah, xh1, accS[t][1]);
      accS[t][1] = MFMA(al, xh1, accS[t][1]);
    }
    #pragma unroll
    for (int t = 0; t < 4; ++t) {
      const int row = 128 + t * 16 + l15;
      const int sw = 8 * (lg ^ ((row >> 1) & 3));
      const bf8 ah = *(const bf8*)(LDS + cbuf + row * 32 + sw);
      const bf8 al = *(const bf8*)(LDS + cbuf + 6144 + row * 32 + sw);
      accA[t][0] = MFMA(ah, xh0, accA[t][0]);
      accA[t][0] = MFMA(al, xh0, accA[t][0]);
      accA[t][1] = MFMA(ah, xh1, accA[t][1]);
      accA[t][1] = MFMA(al, xh1, accA[t][1]);
    }
    bf8 nh0, nh1;
    if (q < 7) {
      #pragma unroll
      for (int jj = 0; jj < 8; ++jj) {
        nh0[jj] = (short)f2b(xRaw[(q + 1) & 1][jj]);
        nh1[jj] = (short)f2b(xRaw[(q + 1) & 1][8 + jj]);
      }
    }
    __syncthreads();
    if (q < 7) {
      *(bf8*)(LDS + xo0) = nh0;
      *(bf8*)(LDS + xo1) = nh1;
      BAR();
    }
  }

  // ================= SOFTMAX + E + Wy(0) =================
  bf8 wReg[4];
  #pragma unroll
  for (int j = 0; j < 4; ++j) wReg[j] = *(const bf8*)(wSrc[j]);

  u16* E = LDS;
  #pragma unroll
  for (int s = 0; s < 2; ++s) {
    const int ps = p + s * 64;
    float mx = -3.0e38f;
    #pragma unroll
    for (int t = 0; t < 8; ++t)
      #pragma unroll
      for (int r = 0; r < 4; ++r) mx = fmaxf(mx, accS[t][s][r]);
    mx = fmaxf(mx, __shfl_xor(mx, 16));
    mx = fmaxf(mx, __shfl_xor(mx, 32));
    float sum = 0.f;
    #pragma unroll
    for (int t = 0; t < 8; ++t)
      #pragma unroll
      for (int r = 0; r < 4; ++r) {
        const float e = __expf(accS[t][s][r] - mx);
        accS[t][s][r] = e; sum += e;
      }
    sum += __shfl_xor(sum, 16);
    sum += __shfl_xor(sum, 32);
    const float rcp = 1.f / sum;
    #pragma unroll
    for (int t = 0; t < 8; ++t) {
      const int j0 = t * 16 + lg * 4;
      const int chunk = j0 >> 3;
      const int csw = (chunk & ~7) | ((chunk & 7) ^ (ps & 7));
      st4(E + ps * 192 + csw * 8 + (j0 & 7),
          f2b(accS[t][s][0] * rcp), f2b(accS[t][s][1] * rcp),
          f2b(accS[t][s][2] * rcp), f2b(accS[t][s][3] * rcp));
    }
    float mx2 = -3.0e38f;
    #pragma unroll
    for (int t = 0; t < 4; ++t)
      #pragma unroll
      for (int r = 0; r < 4; ++r) mx2 = fmaxf(mx2, accA[t][s][r]);
    mx2 = fmaxf(mx2, __shfl_xor(mx2, 16));
    mx2 = fmaxf(mx2, __shfl_xor(mx2, 32));
    float sum2 = 0.f;
    #pragma unroll
    for (int t = 0; t < 4; ++t)
      #pragma unroll
      for (int r = 0; r < 4; ++r) {
        const float e = __expf(accA[t][s][r] - mx2);
        accA[t][s][r] = e; sum2 += e;
      }
    sum2 += __shfl_xor(sum2, 16);
    sum2 += __shfl_xor(sum2, 32);
    const float rcp2 = 1.f / sum2;
    #pragma unroll
    for (int t = 0; t < 4; ++t) {
      const int j0 = 128 + t * 16 + lg * 4;
      const int chunk = j0 >> 3;
      const int csw = (chunk & ~7) | ((chunk & 7) ^ (ps & 7));
      st4(E + ps * 192 + csw * 8 + (j0 & 7),
          f2b(accA[t][s][0] * rcp2), f2b(accA[t][s][1] * rcp2),
          f2b(accA[t][s][2] * rcp2), f2b(accA[t][s][3] * rcp2));
    }
  }
  #pragma unroll
  for (int j = 0; j < 4; ++j) *(bf8*)(LDS + wLds[j]) = wReg[j];
  BAR();

  // ================= OUT PHASE: y = Wy @ E (K=192, 6 steps) ===============
  f4 acc8[16][2];
  #pragma unroll
  for (int t = 0; t < 16; ++t) { acc8[t][0] = zero4; acc8[t][1] = zero4; }

  #pragma unroll
  for (int q = 0; q < 6; ++q) {
    if (q < 5) {
      #pragma unroll
      for (int j = 0; j < 4; ++j) wReg[j] = *(const bf8*)(wSrc[j] + (q + 1) * 32);
    }
    const int jchunk = q * 4 + lg;
    const int cs0 = (jchunk & ~7) | ((jchunk & 7) ^ (p & 7));
    const bf8 ef0 = *(const bf8*)(E + p * 192 + cs0 * 8);
    const bf8 ef1 = *(const bf8*)(E + (p + 64) * 192 + cs0 * 8);
    #pragma unroll
    for (int t = 0; t < 16; ++t) {
      const int row = t * 16 + l15;
      const int sw = 8 * (lg ^ ((row >> 1) & 3));
      const bf8 wf = *(const bf8*)(LDS + 24576 + row * 32 + sw);
      acc8[t][0] = MFMA(wf, ef0, acc8[t][0]);
      acc8[t][1] = MFMA(wf, ef1, acc8[t][1]);
    }
    BAR();
    if (q < 5) {
      #pragma unroll
      for (int j = 0; j < 4; ++j) *(bf8*)(LDS + wLds[j]) = wReg[j];
      BAR();
    }
  }

  // ================= EPILOGUE =================
  const size_t pcol = (size_t)p0g + p;
  #pragma unroll
  for (int t = 0; t < 16; ++t) {
    #pragma unroll
    for (int r = 0; r < 4; ++r) {
      const int c = t * 16 + lg * 4 + r;
      const float sc = scL[c], bi = biL[c];
      const size_t o0 = (((size_t)b * 256 + c) << 13) + pcol;
      const float z0 = x[o0] + acc8[t][0][r] * sc + bi;
      out[o0] = z0 > 0.f ? z0 : 0.2f * z0;
      const size_t o1 = o0 + 64;
      const float z1 = x[o1] + acc8[t][1][r] * sc + bi;
      out[o1] = z1 > 0.f ? z1 : 0.2f * z1;
    }
  }
}

// ---------------------------------------------------------------------------
extern "C" void kernel_launch(void* const* d_in, const int* in_sizes, int n_in,
                              void* d_out, int out_size, void* d_ws, size_t ws_size,
                              hipStream_t stream) {
  const float* x      = (const float*)d_in[0];
  const float* curves = (const float*)d_in[1];
  const float* w_att  = (const float*)d_in[2];
  const float* wa     = (const float*)d_in[3];
  const float* wb     = (const float*)d_in[4];
  const float* wc     = (const float*)d_in[5];
  const float* wn     = (const float*)d_in[6];
  const float* wl     = (const float*)d_in[7];
  const float* wd     = (const float*)d_in[8];
  const float* bng    = (const float*)d_in[9];
  const float* bnb    = (const float*)d_in[10];
  const float* bnm    = (const float*)d_in[11];
  const float* bnv    = (const float*)d_in[12];
  float* out = (float*)d_out;
  float* ws  = (float*)d_ws;
  u16* wsb = (u16*)d_ws;

  if (ws_size >= (size_t)2359296 * 4) {
    // ---- race-free layout (9 MiB), merged launches (5 kernels) ----
    // f32: wdnT@0 wdlT@32768 | smi@131072 sma@262144 | attp@393216..917504
    //      Wac@917504 Wna@983040 Wbc@1048576 Wlb@1114112 (end 1179648)
    //      cinter@1179648..1703936 cintra@1703936..1966080
    //      Wyp(u16)@f32 1966080..2359296
    // u16 outs An/Bl overlay f32 [0..786432) (attp/smi/sma/wdnT all dead).
    float* wdnT   = ws + 0;
    float* wdlT   = ws + 32768;
    float* smi    = ws + 131072;
    float* sma    = ws + 262144;
    float* attp   = ws + 393216;
    float* Wac    = ws + 917504;
    float* Wna    = ws + 983040;
    float* Wbc    = ws + 1048576;
    float* Wlb    = ws + 1114112;
    float* cinter = ws + 1179648;
    float* cintra = ws + 1703936;
    u16* AnH = wsb;
    u16* AnL = wsb + 524288;
    u16* BlH = wsb + 1048576;
    u16* BlL = wsb + 1310720;
    u16* Wyp = wsb + 3932160;

    k_att_wf<<<dim3(1280),   dim3(256), 0, stream>>>(curves, w_att, attp,
                                                     wd, wn, wl, wdnT, wdlT, 1024);
    k_sm_wf2<<<dim3(1040),   dim3(256), 0, stream>>>(attp, smi, sma, wa, wb, wc,
                                                     wdnT, wdlT, Wac, Wna, Wbc, Wlb, 16);
    k_agg   <<<dim3(B_ * C_), dim3(256), 0, stream>>>(curves, smi, sma, cinter, cintra);
    k_fold  <<<dim3(B_ * 24), dim3(256), 0, stream>>>(cinter, cintra,
                                                      Wac, Wna, Wbc, Wlb,
                                                      AnH, AnL, BlH, BlL, Wyp);
    k_big   <<<dim3(1024),   dim3(256), 0, stream>>>(x, AnH, AnL, BlH, BlL, Wyp,
                                                     bng, bnb, bnm, bnv, out);
  } else {
    // ---- fallback: r18 layout & sequence (7.5 MiB proven) ----
    float* smi    = ws + 131072;
    float* sma    = ws + 262144;
    float* cinter = ws + 393216;
    float* cintra = ws + 917504;
    float* attp   = ws + 1179648;
    float* Wac    = ws + 1179648;
    float* Wna    = ws + 1245184;
    float* Wbc    = ws + 1310720;
    float* Wlb    = ws + 1376256;
    float* wdnT   = ws + 1441792;
    float* wdlT   = ws + 1474560;
    u16* AnH = wsb;
    u16* AnL = wsb + 524288;
    u16* BlH = wsb + 1048576;
    u16* BlL = wsb + 1310720;
    u16* Wyp = wsb + 1572864;

    k_att_wf<<<dim3(1024),   dim3(256), 0, stream>>>(curves, w_att, attp,
                                                     wd, wn, wl, wdnT, wdlT, 1024);
    k_sm_wf2<<<dim3(16),     dim3(256), 0, stream>>>(attp, smi, sma, wa, wb, wc,
                                                     wdnT, wdlT, Wac, Wna, Wbc, Wlb, 16);
    k_att_wf<<<dim3(256),    dim3(256), 0, stream>>>(curves, w_att, attp,
                                                     wd, wn, wl, wdnT, wdlT, 0);
    k_sm_wf2<<<dim3(1024),   dim3(256), 0, stream>>>(attp, smi, sma, wa, wb, wc,
                                                     wdnT, wdlT, Wac, Wna, Wbc, Wlb, 0);
    k_agg   <<<dim3(B_ * C_), dim3(256), 0, stream>>>(curves, smi, sma, cinter, cintra);
    k_fold  <<<dim3(B_ * 24), dim3(256), 0, stream>>>(cinter, cintra,
                                                      Wac, Wna, Wbc, Wlb,
                                                      AnH, AnL, BlH, BlL, Wyp);
    k_big   <<<dim3(1024),   dim3(256), 0, stream>>>(x, AnH, AnL, BlH, BlL, Wyp,
                                                     bng, bnb, bnm, bnv, out);
  }
}